// Round 4
// baseline (138.810 us; speedup 1.0000x reference)
//
#include <hip/hip_runtime.h>
#include <hip/hip_bf16.h>

#define NBLK 4096
#define BS 32
#define CH 128

typedef float f32x4 __attribute__((ext_vector_type(4)));
typedef short bf16x8 __attribute__((ext_vector_type(8)));
typedef unsigned short u16x4 __attribute__((ext_vector_type(4)));

__device__ __forceinline__ short f2b(float x) {
    return __builtin_bit_cast(short, __float2bfloat16(x));
}
__device__ __forceinline__ float b2f(unsigned short h) {
    union { unsigned u; float f; } c; c.u = ((unsigned)h) << 16; return c.f;
}
__device__ __forceinline__ u16x4 pack4(f32x4 a) {
    u16x4 o;
    o[0] = (unsigned short)f2b(a[0]); o[1] = (unsigned short)f2b(a[1]);
    o[2] = (unsigned short)f2b(a[2]); o[3] = (unsigned short)f2b(a[3]);
    return o;
}
__device__ __forceinline__ bf16x8 pack8(f32x4 a, f32x4 b) {
    bf16x8 o;
    o[0] = f2b(a[0]); o[1] = f2b(a[1]); o[2] = f2b(a[2]); o[3] = f2b(a[3]);
    o[4] = f2b(b[0]); o[5] = f2b(b[1]); o[6] = f2b(b[2]); o[7] = f2b(b[3]);
    return o;
}
// swizzled index (shorts) within a [32 rows][32 cols] bf16 head-chunk (2KB).
// 16B chunk index XORed with row bits -> balanced 8 lanes per 16B-group for
// every access pattern in this kernel (verified analytically per pattern).
__device__ __forceinline__ int swz(int row, int col) {
    return (row << 5) + ((((col >> 3) ^ ((row >> 1) & 3)) << 3) | (col & 7));
}

// --- pre-kernel: convert weights to bf16 into workspace -------------------
__global__ void convert_weights(const float* __restrict__ wqkv,
                                const float* __restrict__ wproj,
                                short* __restrict__ wsout) {
    int i = blockIdx.x * 256 + threadIdx.x;          // 0 .. 65535
    if (i < 3 * CH * CH) {
        wsout[i] = f2b(wqkv[i]);
    } else {
        int j = i - 3 * CH * CH;
        if (j < CH * CH) wsout[3 * CH * CH + j] = f2b(wproj[j]);
    }
}

// --- main fused kernel: one workgroup per 32-token block ------------------
// Wave w owns head w end-to-end. LDS: 3 regions x 8KB = 24KB -> 6 blocks/CU.
//   Rv: vt  [4][32 dim][32 s]   (V^T per head)
//   Rq: q   [4][32 tok][32 dim] -> x_out (PV result) after 2a
//   Rk: k   [4][32 s][32 dim]   -> comb [32 q][32 s] after 2a
// Single __syncthreads() before the proj GEMM (only cross-wave dependency).
__launch_bounds__(256, 6)
__global__ void fused_block_attn(
    const float* __restrict__ x,
    const float* __restrict__ edge_feats,
    const float* __restrict__ bqkv,
    const float* __restrict__ bproj,
    const float* __restrict__ wgate,
    const float* __restrict__ bgate,
    const int*   __restrict__ attn_mask,
    const short* __restrict__ wqkv_b,    // [384][128] bf16
    const short* __restrict__ wproj_b,   // [128][128] bf16
    float* __restrict__ out)
{
    const int b    = blockIdx.x;
    const int tid  = threadIdx.x;
    const int lane = tid & 63;
    const int w    = tid >> 6;
    const int lm   = lane & 15;
    const int g    = lane >> 4;
    const int ak   = g * 8;            // k-offset (elements) within K=32
    const int rb   = g * 4;            // D-row base within tile

    __shared__ short Rv[4096];
    __shared__ short Rq[4096];
    __shared__ short Rk[4096];
    short* vt = Rv + w * 1024;
    short* qc = Rq + w * 1024;
    short* kc = Rk + w * 1024;

    // ---- load x token-fragments directly from global (L2/L3-hot) --------
    const float* xb = x + (size_t)b * (BS * CH);
    bf16x8 kvf[2][4];
    #pragma unroll
    for (int kk = 0; kk < 4; ++kk) {
        const float* p0 = xb + lm * CH + kk * 32 + ak;
        const float* p1 = p0 + 16 * CH;
        kvf[0][kk] = pack8(*(const f32x4*)p0, *(const f32x4*)(p0 + 4));
        kvf[1][kk] = pack8(*(const f32x4*)p1, *(const f32x4*)(p1 + 4));
    }

    // ---- phase 1: own-head q,k (swapped orient) and v (normal) ----------
    #pragma unroll
    for (int t = 0; t < 4; ++t) {          // q0,q1,k0,k1
        const int o0 = ((t >> 1) ? CH : 0) + w * 32 + (t & 1) * 16;
        const short* wp = wqkv_b + (o0 + lm) * CH + ak;
        bf16x8 wf[4];
        #pragma unroll
        for (int kk = 0; kk < 4; ++kk) wf[kk] = *(const bf16x8*)(wp + kk * 32);
        f32x4 acc0 = *(const f32x4*)(bqkv + o0 + rb);   // bias per out-dim row
        f32x4 acc1 = acc0;
        #pragma unroll
        for (int kk = 0; kk < 4; ++kk) {
            acc0 = __builtin_amdgcn_mfma_f32_16x16x32_bf16(wf[kk], kvf[0][kk], acc0, 0, 0, 0);
            acc1 = __builtin_amdgcn_mfma_f32_16x16x32_bf16(wf[kk], kvf[1][kk], acc1, 0, 0, 0);
        }
        // D[outdim rb+j][token lm] -> store [token][dim] (4 consecutive dims)
        short* dst = (t >> 1) ? kc : qc;
        const int c0 = (t & 1) * 16 + rb;
        *(u16x4*)&dst[swz(lm, c0)]      = pack4(acc0);
        *(u16x4*)&dst[swz(16 + lm, c0)] = pack4(acc1);
    }
    #pragma unroll
    for (int t = 0; t < 2; ++t) {          // v0,v1
        const int o0 = 2 * CH + w * 32 + t * 16;
        const short* wp = wqkv_b + (o0 + lm) * CH + ak;
        bf16x8 wf[4];
        #pragma unroll
        for (int kk = 0; kk < 4; ++kk) wf[kk] = *(const bf16x8*)(wp + kk * 32);
        float bv = bqkv[o0 + lm];
        f32x4 acc0 = {bv, bv, bv, bv};
        f32x4 acc1 = acc0;
        #pragma unroll
        for (int kk = 0; kk < 4; ++kk) {
            acc0 = __builtin_amdgcn_mfma_f32_16x16x32_bf16(kvf[0][kk], wf[kk], acc0, 0, 0, 0);
            acc1 = __builtin_amdgcn_mfma_f32_16x16x32_bf16(kvf[1][kk], wf[kk], acc1, 0, 0, 0);
        }
        // D[token rb+j][outdim lm] -> store V^T [dim][token] (4 consec tokens)
        const int row = t * 16 + lm;       // head-local dim
        *(u16x4*)&vt[swz(row, rb)]      = pack4(acc0);
        *(u16x4*)&vt[swz(row, 16 + rb)] = pack4(acc1);
    }

    // ---- phase 2a: scores^T = K @ Q^T (own wave, no barrier) -------------
    {
        bf16x8 af0 = *(const bf16x8*)&kc[swz(lm, ak)];
        bf16x8 af1 = *(const bf16x8*)&kc[swz(16 + lm, ak)];
        bf16x8 bq0 = *(const bf16x8*)&qc[swz(lm, ak)];
        bf16x8 bq1 = *(const bf16x8*)&qc[swz(16 + lm, ak)];
        f32x4 z = {0.f, 0.f, 0.f, 0.f};
        f32x4 s00 = __builtin_amdgcn_mfma_f32_16x16x32_bf16(af0, bq0, z, 0, 0, 0); // D[s][q]
        f32x4 s10 = __builtin_amdgcn_mfma_f32_16x16x32_bf16(af1, bq0, z, 0, 0, 0);
        f32x4 s01 = __builtin_amdgcn_mfma_f32_16x16x32_bf16(af0, bq1, z, 0, 0, 0);
        f32x4 s11 = __builtin_amdgcn_mfma_f32_16x16x32_bf16(af1, bq1, z, 0, 0, 0);
        const float SC = 0.17677669529663689f;
        // comb[q][s] (overwrites k region; reads above precede writes in-wave)
        *(u16x4*)&kc[swz(lm, rb)]           = pack4(s00 * SC);
        *(u16x4*)&kc[swz(lm, 16 + rb)]      = pack4(s10 * SC);
        *(u16x4*)&kc[swz(16 + lm, rb)]      = pack4(s01 * SC);
        *(u16x4*)&kc[swz(16 + lm, 16 + rb)] = pack4(s11 * SC);
    }

    // ---- phase 2b: softmax + edge gate (own wave: r=lane>>1, half=lane&1) -
    {
        const int r    = lane >> 1;
        const int half = lane & 1;
        bf16x8 t0 = *(const bf16x8*)&kc[swz(r, half * 16)];
        bf16x8 t1 = *(const bf16x8*)&kc[swz(r, half * 16 + 8)];

        float sd = 0.f;
        #pragma unroll
        for (int j = 0; j < 8; ++j)
            sd += b2f((unsigned short)t0[j]) + b2f((unsigned short)t1[j]);
        sd += __shfl_xor(sd, 1);
        const float d32 = sd * 0.03125f;            // q . mean(k), scaled

        const float* efb = edge_feats + ((size_t)((b * BS + r) * 33 + half * 16)) * 4;
        const int*   mkb = attn_mask + (size_t)(b * BS + r) * 33 + half * 16;
        f32x4 wg = *(const f32x4*)(wgate + w * 4);
        float bg = bgate[w];

        float e[16], lw[16];
        float se = 0.f;
        #pragma unroll
        for (int s = 0; s < 16; ++s) {
            float dv = (s < 8) ? b2f((unsigned short)t0[s]) : b2f((unsigned short)t1[s - 8]);
            f32x4 ef = *(const f32x4*)(efb + s * 4);
            bool diag = (half * 16 + s) == r;
            float ef0 = diag ? 0.f : ef[0];
            float ef1 = diag ? 0.f : ef[1];
            float ef2 = diag ? 0.f : ef[2];
            float ef3 = diag ? 1.f : ef[3];
            int m = mkb[s];
            lw[s] = m ? (ef0 * wg[0] + ef1 * wg[1] + ef2 * wg[2] + ef3 * wg[3] + bg) : 0.f;
            e[s]  = m ? __expf(dv + ef3) : 0.f;     // no max-sub: |score| <~ 8
            se += e[s];
        }
        const float e32 = __expf(d32 + 1.0f);       // global token (always attendable)
        const float tot = se + __shfl_xor(se, 1) + e32;
        const float rinv = 1.0f / tot;
        const float add32 = (e32 * rinv + wg[3] + bg) * 0.03125f;  // fold global col

        #pragma unroll
        for (int pk = 0; pk < 4; ++pk) {
            f32x4 v;
            #pragma unroll
            for (int j = 0; j < 4; ++j)
                v[j] = e[pk * 4 + j] * rinv + lw[pk * 4 + j] + add32;
            *(u16x4*)&kc[swz(r, half * 16 + pk * 4)] = pack4(v);
        }
    }

    // ---- phase 3: x_out = V^T-style PV (own wave) -------------------------
    {
        bf16x8 av0 = *(const bf16x8*)&vt[swz(lm, ak)];
        bf16x8 av1 = *(const bf16x8*)&vt[swz(16 + lm, ak)];
        bf16x8 bc0 = *(const bf16x8*)&kc[swz(lm, ak)];
        bf16x8 bc1 = *(const bf16x8*)&kc[swz(16 + lm, ak)];
        f32x4 z = {0.f, 0.f, 0.f, 0.f};
        f32x4 x00 = __builtin_amdgcn_mfma_f32_16x16x32_bf16(av0, bc0, z, 0, 0, 0); // D[d][q]
        f32x4 x10 = __builtin_amdgcn_mfma_f32_16x16x32_bf16(av1, bc0, z, 0, 0, 0);
        f32x4 x01 = __builtin_amdgcn_mfma_f32_16x16x32_bf16(av0, bc1, z, 0, 0, 0);
        f32x4 x11 = __builtin_amdgcn_mfma_f32_16x16x32_bf16(av1, bc1, z, 0, 0, 0);
        // x_out[q][dim] into q region (q dead after 2a)
        *(u16x4*)&qc[swz(lm, rb)]           = pack4(x00);
        *(u16x4*)&qc[swz(lm, 16 + rb)]      = pack4(x10);
        *(u16x4*)&qc[swz(16 + lm, rb)]      = pack4(x01);
        *(u16x4*)&qc[swz(16 + lm, 16 + rb)] = pack4(x11);
    }

    // ---- prefetch Wproj fragments + bias into regs, then the ONE barrier --
    bf16x8 pw[2][4];
    float pb[2];
    #pragma unroll
    for (int t = 0; t < 2; ++t) {
        int col = w * 32 + t * 16 + lm;
        pb[t] = bproj[col];
        #pragma unroll
        for (int kk = 0; kk < 4; ++kk)
            pw[t][kk] = *(const bf16x8*)(wproj_b + col * CH + kk * 32 + ak);
    }
    __syncthreads();

    // ---- phase 4: out = x_out @ Wproj^T + bproj ---------------------------
    {
        bf16x8 a2[2][4];
        #pragma unroll
        for (int kk = 0; kk < 4; ++kk) {
            a2[0][kk] = *(const bf16x8*)&Rq[kk * 1024 + swz(lm, ak)];
            a2[1][kk] = *(const bf16x8*)&Rq[kk * 1024 + swz(16 + lm, ak)];
        }
        float* ob = out + (size_t)b * BS * CH;
        #pragma unroll
        for (int t = 0; t < 2; ++t) {
            int col = w * 32 + t * 16 + lm;
            f32x4 acc0 = {pb[t], pb[t], pb[t], pb[t]};
            f32x4 acc1 = acc0;
            #pragma unroll
            for (int kk = 0; kk < 4; ++kk) {
                acc0 = __builtin_amdgcn_mfma_f32_16x16x32_bf16(a2[0][kk], pw[t][kk], acc0, 0, 0, 0);
                acc1 = __builtin_amdgcn_mfma_f32_16x16x32_bf16(a2[1][kk], pw[t][kk], acc1, 0, 0, 0);
            }
            #pragma unroll
            for (int j = 0; j < 4; ++j) {
                ob[(rb + j) * CH + col]      = acc0[j];
                ob[(16 + rb + j) * CH + col] = acc1[j];
            }
        }
    }
}

extern "C" void kernel_launch(void* const* d_in, const int* in_sizes, int n_in,
                              void* d_out, int out_size, void* d_ws, size_t ws_size,
                              hipStream_t stream) {
    const float* x          = (const float*)d_in[0];
    const float* edge_feats = (const float*)d_in[1];
    const float* Wqkv       = (const float*)d_in[2];
    const float* bqkv       = (const float*)d_in[3];
    const float* Wproj      = (const float*)d_in[4];
    const float* bproj      = (const float*)d_in[5];
    const float* Wgate      = (const float*)d_in[6];
    const float* bgate      = (const float*)d_in[7];
    const int*   attn_mask  = (const int*)d_in[8];
    float* out = (float*)d_out;
    short* wb  = (short*)d_ws;

    convert_weights<<<256, 256, 0, stream>>>(Wqkv, Wproj, wb);
    fused_block_attn<<<NBLK, 256, 0, stream>>>(
        x, edge_feats, bqkv, bproj, Wgate, bgate, attn_mask,
        wb, wb + 3 * CH * CH, out);
}

// Round 6
// 110.339 us; speedup vs baseline: 1.2580x; 1.2580x over previous
//
#include <hip/hip_runtime.h>
#include <hip/hip_bf16.h>

#define NBLK 4096
#define BS 32
#define CH 128

typedef float f32x4 __attribute__((ext_vector_type(4)));
typedef short bf16x8 __attribute__((ext_vector_type(8)));
typedef unsigned short u16x4 __attribute__((ext_vector_type(4)));

__device__ __forceinline__ short f2b(float x) {
    return __builtin_bit_cast(short, __float2bfloat16(x));
}
__device__ __forceinline__ float b2f(unsigned short h) {
    union { unsigned u; float f; } c; c.u = ((unsigned)h) << 16; return c.f;
}
__device__ __forceinline__ u16x4 pack4(f32x4 a) {
    u16x4 o;
    o[0] = (unsigned short)f2b(a[0]); o[1] = (unsigned short)f2b(a[1]);
    o[2] = (unsigned short)f2b(a[2]); o[3] = (unsigned short)f2b(a[3]);
    return o;
}
__device__ __forceinline__ bf16x8 pack8(f32x4 a, f32x4 b) {
    bf16x8 o;
    o[0] = f2b(a[0]); o[1] = f2b(a[1]); o[2] = f2b(a[2]); o[3] = f2b(a[3]);
    o[4] = f2b(b[0]); o[5] = f2b(b[1]); o[6] = f2b(b[2]); o[7] = f2b(b[3]);
    return o;
}
// swizzled index (shorts) within a [32 rows][32 cols] bf16 head-chunk (2KB)
__device__ __forceinline__ int swz(int row, int col) {
    return (row << 5) + ((((col >> 3) ^ ((row >> 1) & 3)) << 3) | (col & 7));
}

// --- pre-kernel: convert weights to bf16 into workspace -------------------
__global__ void convert_weights(const float* __restrict__ wqkv,
                                const float* __restrict__ wproj,
                                short* __restrict__ wsout) {
    int i = blockIdx.x * 256 + threadIdx.x;          // 0 .. 65535
    if (i < 3 * CH * CH) {
        wsout[i] = f2b(wqkv[i]);
    } else {
        int j = i - 3 * CH * CH;
        if (j < CH * CH) wsout[3 * CH * CH + j] = f2b(wproj[j]);
    }
}

// --- main fused kernel: one workgroup per 32-token block ------------------
// Wave w owns head w. Phases:
//   0.5: HBM ef/mask stream issued FIRST; staged RAW (f32 ef + mask bits)
//        [barrier]
//   1:   QKV via MFMA (x + weights, L2-hot)
//   2a:  scores^T via MFMA (wave-private)
//   2b:  softmax + gate — R4 math verbatim, ef from LDS (bit-exact)
//   3:   PV via MFMA (wave-private)                  [barrier]
//   4:   proj GEMM via MFMA
// LDS: 3x8KB + efS 16KB + maskW 128B = 28800B -> 5 blocks/CU.
__launch_bounds__(256, 4)
__global__ void fused_block_attn(
    const float* __restrict__ x,
    const float* __restrict__ edge_feats,
    const float* __restrict__ bqkv,
    const float* __restrict__ bproj,
    const float* __restrict__ wgate,
    const float* __restrict__ bgate,
    const int*   __restrict__ attn_mask,
    const short* __restrict__ wqkv_b,    // [384][128] bf16
    const short* __restrict__ wproj_b,   // [128][128] bf16
    float* __restrict__ out)
{
    const int b    = blockIdx.x;
    const int tid  = threadIdx.x;
    const int lane = tid & 63;
    const int w    = tid >> 6;
    const int lm   = lane & 15;
    const int g    = lane >> 4;
    const int ak   = g * 8;            // k-offset (elements) within K=32
    const int rb   = g * 4;            // D-row base within tile

    __shared__ short Rv[4096];
    __shared__ short Rq[4096];
    __shared__ short Rk[4096];
    __shared__ float efS[32 * 128];    // raw ef: [r][(s^(r&7))*4 + f]
    __shared__ unsigned maskW[32];     // bit s of word r = mask[r][s]
    short* vt = Rv + w * 1024;
    short* qc = Rq + w * 1024;
    short* kc = Rk + w * 1024;

    // ---- Phase 0.5a: issue the HBM stream FIRST ---------------------------
    const int pr = tid >> 3;           // row 0..31
    const int pu = tid & 7;            // s-group; s = pu*4 .. pu*4+3
    const float* efp = edge_feats + ((size_t)(b * BS + pr) * 33 + pu * 4) * 4;
    f32x4 ef0 = ((const f32x4*)efp)[0];
    f32x4 ef1 = ((const f32x4*)efp)[1];
    f32x4 ef2 = ((const f32x4*)efp)[2];
    f32x4 ef3v = ((const f32x4*)efp)[3];
    const int* mkp = attn_mask + (size_t)(b * BS + pr) * 33 + pu * 4;
    const int m0 = mkp[0], m1 = mkp[1], m2 = mkp[2], m3 = mkp[3];

    // ---- Phase 0.5b: stage RAW ef (diag pre-overridden) + mask bits -------
    {
        #pragma unroll
        for (int j = 0; j < 4; ++j) {
            f32x4 e = (j == 0) ? ef0 : (j == 1) ? ef1 : (j == 2) ? ef2 : ef3v;
            const int s = pu * 4 + j;
            if (s == pr) { e[0] = 0.f; e[1] = 0.f; e[2] = 0.f; e[3] = 1.f; }
            *(f32x4*)&efS[pr * 128 + ((s ^ (pr & 7)) << 2)] = e;
        }
        unsigned bits = (unsigned)(m0 != 0) | ((unsigned)(m1 != 0) << 1)
                      | ((unsigned)(m2 != 0) << 2) | ((unsigned)(m3 != 0) << 3);
        unsigned wbits = bits << (pu * 4);
        wbits |= __shfl_xor(wbits, 1);
        wbits |= __shfl_xor(wbits, 2);
        wbits |= __shfl_xor(wbits, 4);
        if (pu == 0) maskW[pr] = wbits;
    }
    __syncthreads();

    // ---- Phase 1: own-head QKV via MFMA (x + weights all L2-hot) ---------
    const float* xb = x + (size_t)b * (BS * CH);
    bf16x8 kvf[2][4];
    #pragma unroll
    for (int kk = 0; kk < 4; ++kk) {
        const float* p0 = xb + lm * CH + kk * 32 + ak;
        const float* p1 = p0 + 16 * CH;
        kvf[0][kk] = pack8(*(const f32x4*)p0, *(const f32x4*)(p0 + 4));
        kvf[1][kk] = pack8(*(const f32x4*)p1, *(const f32x4*)(p1 + 4));
    }

    #pragma unroll
    for (int t = 0; t < 4; ++t) {          // q0,q1,k0,k1 (swapped orient)
        const int o0 = ((t >> 1) ? CH : 0) + w * 32 + (t & 1) * 16;
        const short* wp = wqkv_b + (o0 + lm) * CH + ak;
        bf16x8 wf[4];
        #pragma unroll
        for (int kk = 0; kk < 4; ++kk) wf[kk] = *(const bf16x8*)(wp + kk * 32);
        f32x4 acc0 = *(const f32x4*)(bqkv + o0 + rb);
        f32x4 acc1 = acc0;
        #pragma unroll
        for (int kk = 0; kk < 4; ++kk) {
            acc0 = __builtin_amdgcn_mfma_f32_16x16x32_bf16(wf[kk], kvf[0][kk], acc0, 0, 0, 0);
            acc1 = __builtin_amdgcn_mfma_f32_16x16x32_bf16(wf[kk], kvf[1][kk], acc1, 0, 0, 0);
        }
        short* dst = (t >> 1) ? kc : qc;
        const int c0 = (t & 1) * 16 + rb;
        *(u16x4*)&dst[swz(lm, c0)]      = pack4(acc0);
        *(u16x4*)&dst[swz(16 + lm, c0)] = pack4(acc1);
    }
    #pragma unroll
    for (int t = 0; t < 2; ++t) {          // v0,v1 (normal orient -> V^T)
        const int o0 = 2 * CH + w * 32 + t * 16;
        const short* wp = wqkv_b + (o0 + lm) * CH + ak;
        bf16x8 wf[4];
        #pragma unroll
        for (int kk = 0; kk < 4; ++kk) wf[kk] = *(const bf16x8*)(wp + kk * 32);
        float bv = bqkv[o0 + lm];
        f32x4 acc0 = {bv, bv, bv, bv};
        f32x4 acc1 = acc0;
        #pragma unroll
        for (int kk = 0; kk < 4; ++kk) {
            acc0 = __builtin_amdgcn_mfma_f32_16x16x32_bf16(kvf[0][kk], wf[kk], acc0, 0, 0, 0);
            acc1 = __builtin_amdgcn_mfma_f32_16x16x32_bf16(kvf[1][kk], wf[kk], acc1, 0, 0, 0);
        }
        const int row = t * 16 + lm;
        *(u16x4*)&vt[swz(row, rb)]      = pack4(acc0);
        *(u16x4*)&vt[swz(row, 16 + rb)] = pack4(acc1);
    }

    // ---- Phase 2a: scores^T = K @ Q^T (wave-private) ----------------------
    {
        bf16x8 af0 = *(const bf16x8*)&kc[swz(lm, ak)];
        bf16x8 af1 = *(const bf16x8*)&kc[swz(16 + lm, ak)];
        bf16x8 bq0 = *(const bf16x8*)&qc[swz(lm, ak)];
        bf16x8 bq1 = *(const bf16x8*)&qc[swz(16 + lm, ak)];
        f32x4 z = {0.f, 0.f, 0.f, 0.f};
        f32x4 s00 = __builtin_amdgcn_mfma_f32_16x16x32_bf16(af0, bq0, z, 0, 0, 0);
        f32x4 s10 = __builtin_amdgcn_mfma_f32_16x16x32_bf16(af1, bq0, z, 0, 0, 0);
        f32x4 s01 = __builtin_amdgcn_mfma_f32_16x16x32_bf16(af0, bq1, z, 0, 0, 0);
        f32x4 s11 = __builtin_amdgcn_mfma_f32_16x16x32_bf16(af1, bq1, z, 0, 0, 0);
        const float SC = 0.17677669529663689f;
        *(u16x4*)&kc[swz(lm, rb)]           = pack4(s00 * SC);
        *(u16x4*)&kc[swz(lm, 16 + rb)]      = pack4(s10 * SC);
        *(u16x4*)&kc[swz(16 + lm, rb)]      = pack4(s01 * SC);
        *(u16x4*)&kc[swz(16 + lm, 16 + rb)] = pack4(s11 * SC);
    }

    // ---- Phase 2b: softmax + gate — R4 math verbatim ----------------------
    {
        const int r    = lane >> 1;
        const int half = lane & 1;
        bf16x8 t0 = *(const bf16x8*)&kc[swz(r, half * 16)];
        bf16x8 t1 = *(const bf16x8*)&kc[swz(r, half * 16 + 8)];

        float dv[16];
        #pragma unroll
        for (int j = 0; j < 8; ++j) {
            dv[j]     = b2f((unsigned short)t0[j]);
            dv[8 + j] = b2f((unsigned short)t1[j]);
        }
        float sd = 0.f;
        #pragma unroll
        for (int j = 0; j < 16; ++j) sd += dv[j];
        sd += __shfl_xor(sd, 1);
        const float d32 = sd * 0.03125f;

        const unsigned mw = maskW[r];
        f32x4 wg = *(const f32x4*)(wgate + w * 4);
        float bg = bgate[w];

        float e[16], lw[16];
        float se = 0.f;
        #pragma unroll
        for (int s = 0; s < 16; ++s) {
            const int sg = half * 16 + s;
            f32x4 ef = *(const f32x4*)&efS[r * 128 + ((sg ^ (r & 7)) << 2)];
            const int m = (mw >> sg) & 1;
            lw[s] = m ? (ef[0] * wg[0] + ef[1] * wg[1] + ef[2] * wg[2] + ef[3] * wg[3] + bg) : 0.f;
            e[s]  = m ? __expf(dv[s] + ef[3]) : 0.f;
            se += e[s];
        }
        const float e32 = __expf(d32 + 1.0f);       // global token
        const float tot = se + __shfl_xor(se, 1) + e32;
        const float rinv = 1.0f / tot;
        const float add32 = (e32 * rinv + wg[3] + bg) * 0.03125f;

        #pragma unroll
        for (int pk = 0; pk < 4; ++pk) {
            f32x4 v;
            #pragma unroll
            for (int j = 0; j < 4; ++j) {
                int idx = pk * 4 + j;
                v[j] = e[idx] * rinv + lw[idx] + add32;
            }
            *(u16x4*)&kc[swz(r, half * 16 + pk * 4)] = pack4(v);
        }
    }

    // ---- Phase 3: x_out = V^T @ comb^T via MFMA (wave-private) ------------
    {
        bf16x8 av0 = *(const bf16x8*)&vt[swz(lm, ak)];
        bf16x8 av1 = *(const bf16x8*)&vt[swz(16 + lm, ak)];
        bf16x8 bc0 = *(const bf16x8*)&kc[swz(lm, ak)];
        bf16x8 bc1 = *(const bf16x8*)&kc[swz(16 + lm, ak)];
        f32x4 z = {0.f, 0.f, 0.f, 0.f};
        f32x4 x00 = __builtin_amdgcn_mfma_f32_16x16x32_bf16(av0, bc0, z, 0, 0, 0);
        f32x4 x10 = __builtin_amdgcn_mfma_f32_16x16x32_bf16(av1, bc0, z, 0, 0, 0);
        f32x4 x01 = __builtin_amdgcn_mfma_f32_16x16x32_bf16(av0, bc1, z, 0, 0, 0);
        f32x4 x11 = __builtin_amdgcn_mfma_f32_16x16x32_bf16(av1, bc1, z, 0, 0, 0);
        *(u16x4*)&qc[swz(lm, rb)]           = pack4(x00);
        *(u16x4*)&qc[swz(lm, 16 + rb)]      = pack4(x10);
        *(u16x4*)&qc[swz(16 + lm, rb)]      = pack4(x01);
        *(u16x4*)&qc[swz(16 + lm, 16 + rb)] = pack4(x11);
    }

    // ---- prefetch Wproj fragments + bias, then the cross-head barrier -----
    bf16x8 pw[2][4];
    float pb[2];
    #pragma unroll
    for (int t = 0; t < 2; ++t) {
        int col = w * 32 + t * 16 + lm;
        pb[t] = bproj[col];
        #pragma unroll
        for (int kk = 0; kk < 4; ++kk)
            pw[t][kk] = *(const bf16x8*)(wproj_b + col * CH + kk * 32 + ak);
    }
    __syncthreads();

    // ---- Phase 4: out = x_out @ Wproj^T + bproj ---------------------------
    {
        bf16x8 a2[2][4];
        #pragma unroll
        for (int kk = 0; kk < 4; ++kk) {
            a2[0][kk] = *(const bf16x8*)&Rq[kk * 1024 + swz(lm, ak)];
            a2[1][kk] = *(const bf16x8*)&Rq[kk * 1024 + swz(16 + lm, ak)];
        }
        float* ob = out + (size_t)b * BS * CH;
        #pragma unroll
        for (int t = 0; t < 2; ++t) {
            int col = w * 32 + t * 16 + lm;
            f32x4 acc0 = {pb[t], pb[t], pb[t], pb[t]};
            f32x4 acc1 = acc0;
            #pragma unroll
            for (int kk = 0; kk < 4; ++kk) {
                acc0 = __builtin_amdgcn_mfma_f32_16x16x32_bf16(a2[0][kk], pw[t][kk], acc0, 0, 0, 0);
                acc1 = __builtin_amdgcn_mfma_f32_16x16x32_bf16(a2[1][kk], pw[t][kk], acc1, 0, 0, 0);
            }
            #pragma unroll
            for (int j = 0; j < 4; ++j) {
                ob[(rb + j) * CH + col]      = acc0[j];
                ob[(16 + rb + j) * CH + col] = acc1[j];
            }
        }
    }
}

extern "C" void kernel_launch(void* const* d_in, const int* in_sizes, int n_in,
                              void* d_out, int out_size, void* d_ws, size_t ws_size,
                              hipStream_t stream) {
    const float* x          = (const float*)d_in[0];
    const float* edge_feats = (const float*)d_in[1];
    const float* Wqkv       = (const float*)d_in[2];
    const float* bqkv       = (const float*)d_in[3];
    const float* Wproj      = (const float*)d_in[4];
    const float* bproj      = (const float*)d_in[5];
    const float* Wgate      = (const float*)d_in[6];
    const float* bgate      = (const float*)d_in[7];
    const int*   attn_mask  = (const int*)d_in[8];
    float* out = (float*)d_out;
    short* wb  = (short*)d_ws;

    convert_weights<<<256, 256, 0, stream>>>(Wqkv, Wproj, wb);
    fused_block_attn<<<NBLK, 256, 0, stream>>>(
        x, edge_feats, bqkv, bproj, Wgate, bgate, attn_mask,
        wb, wb + 3 * CH * CH, out);
}

// Round 7
// 109.884 us; speedup vs baseline: 1.2632x; 1.0041x over previous
//
#include <hip/hip_runtime.h>
#include <hip/hip_bf16.h>

#define NBLK 4096
#define BS 32
#define CH 128

typedef float f32x4 __attribute__((ext_vector_type(4)));
typedef short bf16x8 __attribute__((ext_vector_type(8)));
typedef unsigned short u16x4 __attribute__((ext_vector_type(4)));

__device__ __forceinline__ short f2b(float x) {
    return __builtin_bit_cast(short, __float2bfloat16(x));
}
__device__ __forceinline__ float b2f(unsigned short h) {
    union { unsigned u; float f; } c; c.u = ((unsigned)h) << 16; return c.f;
}
__device__ __forceinline__ u16x4 pack4(f32x4 a) {
    u16x4 o;
    o[0] = (unsigned short)f2b(a[0]); o[1] = (unsigned short)f2b(a[1]);
    o[2] = (unsigned short)f2b(a[2]); o[3] = (unsigned short)f2b(a[3]);
    return o;
}
__device__ __forceinline__ bf16x8 pack8(f32x4 a, f32x4 b) {
    bf16x8 o;
    o[0] = f2b(a[0]); o[1] = f2b(a[1]); o[2] = f2b(a[2]); o[3] = f2b(a[3]);
    o[4] = f2b(b[0]); o[5] = f2b(b[1]); o[6] = f2b(b[2]); o[7] = f2b(b[3]);
    return o;
}
// swizzled index (shorts) within a [32 rows][32 cols] bf16 head-chunk (2KB)
__device__ __forceinline__ int swz(int row, int col) {
    return (row << 5) + ((((col >> 3) ^ ((row >> 1) & 3)) << 3) | (col & 7));
}

// --- pre-kernel: convert weights to bf16 into workspace -------------------
__global__ void convert_weights(const float* __restrict__ wqkv,
                                const float* __restrict__ wproj,
                                short* __restrict__ wsout) {
    int i = blockIdx.x * 256 + threadIdx.x;          // 0 .. 65535
    if (i < 3 * CH * CH) {
        wsout[i] = f2b(wqkv[i]);
    } else {
        int j = i - 3 * CH * CH;
        if (j < CH * CH) wsout[3 * CH * CH + j] = f2b(wproj[j]);
    }
}

// --- main fused kernel: one workgroup per 32-token block ------------------
// Wave w owns head w. Phases:
//   0.5: HBM ef/mask stream issued FIRST; staged bf16, mask folded as
//        ef3 = -inf (exp gives exact 0)                    [barrier]
//   1:   QKV via MFMA (x + weights, L2-hot)
//   2a:  scores^T via MFMA (wave-private)
//   2b:  softmax + gate (ef bf16 from LDS, sentinel mask)
//   3:   PV via MFMA (wave-private)                        [barrier]
//   4:   proj GEMM via MFMA
// LDS: 3x8192 (Rv,Rq,Rk) + efS 8192 = 32768 B exactly -> 5 blocks/CU.
__launch_bounds__(256, 5)
__global__ void fused_block_attn(
    const float* __restrict__ x,
    const float* __restrict__ edge_feats,
    const float* __restrict__ bqkv,
    const float* __restrict__ bproj,
    const float* __restrict__ wgate,
    const float* __restrict__ bgate,
    const int*   __restrict__ attn_mask,
    const short* __restrict__ wqkv_b,    // [384][128] bf16
    const short* __restrict__ wproj_b,   // [128][128] bf16
    float* __restrict__ out)
{
    const int b    = blockIdx.x;
    const int tid  = threadIdx.x;
    const int lane = tid & 63;
    const int w    = tid >> 6;
    const int lm   = lane & 15;
    const int g    = lane >> 4;
    const int ak   = g * 8;            // k-offset (elements) within K=32
    const int rb   = g * 4;            // D-row base within tile

    __shared__ short Rv[4096];
    __shared__ short Rq[4096];
    __shared__ short Rk[4096];
    __shared__ short efS[4096];        // bf16 ef: [r][chunk^(r&15)][8]
    short* vt = Rv + w * 1024;
    short* qc = Rq + w * 1024;
    short* kc = Rk + w * 1024;

    // ---- Phase 0.5a: issue the HBM stream FIRST ---------------------------
    const int pr = tid >> 3;           // row 0..31
    const int pu = tid & 7;            // s-group; s = pu*4 .. pu*4+3
    const float* efp = edge_feats + ((size_t)(b * BS + pr) * 33 + pu * 4) * 4;
    f32x4 efv[4];
    efv[0] = ((const f32x4*)efp)[0];
    efv[1] = ((const f32x4*)efp)[1];
    efv[2] = ((const f32x4*)efp)[2];
    efv[3] = ((const f32x4*)efp)[3];
    const int* mkp = attn_mask + (size_t)(b * BS + pr) * 33 + pu * 4;
    const int mk4[4] = { mkp[0], mkp[1], mkp[2], mkp[3] };

    // ---- Phase 0.5b: stage bf16 ef; masked -> ef3 = -inf sentinel ---------
    {
        #pragma unroll
        for (int jj = 0; jj < 2; ++jj) {         // chunk = pu*2 + jj
            bf16x8 st;
            #pragma unroll
            for (int h2 = 0; h2 < 2; ++h2) {     // s within chunk
                const int s = pu * 4 + jj * 2 + h2;
                f32x4 e = efv[jj * 2 + h2];
                if (s == pr) { e[0] = 0.f; e[1] = 0.f; e[2] = 0.f; e[3] = 1.f; }
                const float e3 = mk4[jj * 2 + h2] ? e[3] : -INFINITY;
                st[h2 * 4 + 0] = f2b(e[0]);
                st[h2 * 4 + 1] = f2b(e[1]);
                st[h2 * 4 + 2] = f2b(e[2]);
                st[h2 * 4 + 3] = f2b(e3);
            }
            const int chunk = pu * 2 + jj;
            *(bf16x8*)&efS[pr * 128 + ((chunk ^ (pr & 15)) << 3)] = st;
        }
    }
    __syncthreads();

    // ---- Phase 1: own-head QKV via MFMA (x + weights all L2-hot) ---------
    const float* xb = x + (size_t)b * (BS * CH);
    bf16x8 kvf[2][4];
    #pragma unroll
    for (int kk = 0; kk < 4; ++kk) {
        const float* p0 = xb + lm * CH + kk * 32 + ak;
        const float* p1 = p0 + 16 * CH;
        kvf[0][kk] = pack8(*(const f32x4*)p0, *(const f32x4*)(p0 + 4));
        kvf[1][kk] = pack8(*(const f32x4*)p1, *(const f32x4*)(p1 + 4));
    }

    #pragma unroll
    for (int t = 0; t < 4; ++t) {          // q0,q1,k0,k1 (swapped orient)
        const int o0 = ((t >> 1) ? CH : 0) + w * 32 + (t & 1) * 16;
        const short* wp = wqkv_b + (o0 + lm) * CH + ak;
        bf16x8 wf[4];
        #pragma unroll
        for (int kk = 0; kk < 4; ++kk) wf[kk] = *(const bf16x8*)(wp + kk * 32);
        f32x4 acc0 = *(const f32x4*)(bqkv + o0 + rb);
        f32x4 acc1 = acc0;
        #pragma unroll
        for (int kk = 0; kk < 4; ++kk) {
            acc0 = __builtin_amdgcn_mfma_f32_16x16x32_bf16(wf[kk], kvf[0][kk], acc0, 0, 0, 0);
            acc1 = __builtin_amdgcn_mfma_f32_16x16x32_bf16(wf[kk], kvf[1][kk], acc1, 0, 0, 0);
        }
        short* dst = (t >> 1) ? kc : qc;
        const int c0 = (t & 1) * 16 + rb;
        *(u16x4*)&dst[swz(lm, c0)]      = pack4(acc0);
        *(u16x4*)&dst[swz(16 + lm, c0)] = pack4(acc1);
    }
    #pragma unroll
    for (int t = 0; t < 2; ++t) {          // v0,v1 (normal orient -> V^T)
        const int o0 = 2 * CH + w * 32 + t * 16;
        const short* wp = wqkv_b + (o0 + lm) * CH + ak;
        bf16x8 wf[4];
        #pragma unroll
        for (int kk = 0; kk < 4; ++kk) wf[kk] = *(const bf16x8*)(wp + kk * 32);
        float bv = bqkv[o0 + lm];
        f32x4 acc0 = {bv, bv, bv, bv};
        f32x4 acc1 = acc0;
        #pragma unroll
        for (int kk = 0; kk < 4; ++kk) {
            acc0 = __builtin_amdgcn_mfma_f32_16x16x32_bf16(kvf[0][kk], wf[kk], acc0, 0, 0, 0);
            acc1 = __builtin_amdgcn_mfma_f32_16x16x32_bf16(kvf[1][kk], wf[kk], acc1, 0, 0, 0);
        }
        const int row = t * 16 + lm;
        *(u16x4*)&vt[swz(row, rb)]      = pack4(acc0);
        *(u16x4*)&vt[swz(row, 16 + rb)] = pack4(acc1);
    }

    // ---- Phase 2a: scores^T = K @ Q^T (wave-private) ----------------------
    {
        bf16x8 af0 = *(const bf16x8*)&kc[swz(lm, ak)];
        bf16x8 af1 = *(const bf16x8*)&kc[swz(16 + lm, ak)];
        bf16x8 bq0 = *(const bf16x8*)&qc[swz(lm, ak)];
        bf16x8 bq1 = *(const bf16x8*)&qc[swz(16 + lm, ak)];
        f32x4 z = {0.f, 0.f, 0.f, 0.f};
        f32x4 s00 = __builtin_amdgcn_mfma_f32_16x16x32_bf16(af0, bq0, z, 0, 0, 0);
        f32x4 s10 = __builtin_amdgcn_mfma_f32_16x16x32_bf16(af1, bq0, z, 0, 0, 0);
        f32x4 s01 = __builtin_amdgcn_mfma_f32_16x16x32_bf16(af0, bq1, z, 0, 0, 0);
        f32x4 s11 = __builtin_amdgcn_mfma_f32_16x16x32_bf16(af1, bq1, z, 0, 0, 0);
        const float SC = 0.17677669529663689f;
        *(u16x4*)&kc[swz(lm, rb)]           = pack4(s00 * SC);
        *(u16x4*)&kc[swz(lm, 16 + rb)]      = pack4(s10 * SC);
        *(u16x4*)&kc[swz(16 + lm, rb)]      = pack4(s01 * SC);
        *(u16x4*)&kc[swz(16 + lm, 16 + rb)] = pack4(s11 * SC);
    }

    // ---- Phase 2b: softmax + gate (ef bf16, sentinel-masked) --------------
    {
        const int r    = lane >> 1;
        const int half = lane & 1;
        bf16x8 t0 = *(const bf16x8*)&kc[swz(r, half * 16)];
        bf16x8 t1 = *(const bf16x8*)&kc[swz(r, half * 16 + 8)];

        float dv[16];
        #pragma unroll
        for (int j = 0; j < 8; ++j) {
            dv[j]     = b2f((unsigned short)t0[j]);
            dv[8 + j] = b2f((unsigned short)t1[j]);
        }
        float sd = 0.f;
        #pragma unroll
        for (int j = 0; j < 16; ++j) sd += dv[j];
        sd += __shfl_xor(sd, 1);
        const float d32 = sd * 0.03125f;

        f32x4 wg = *(const f32x4*)(wgate + w * 4);
        float bg = bgate[w];

        float e[16], lw[16];
        float se = 0.f;
        #pragma unroll
        for (int pk = 0; pk < 8; ++pk) {
            const int chunk = half * 8 + pk;
            bf16x8 c = *(const bf16x8*)&efS[r * 128 + ((chunk ^ (r & 15)) << 3)];
            #pragma unroll
            for (int h2 = 0; h2 < 2; ++h2) {
                const int idx = pk * 2 + h2;
                const float f0 = b2f((unsigned short)c[h2 * 4 + 0]);
                const float f1 = b2f((unsigned short)c[h2 * 4 + 1]);
                const float f2c = b2f((unsigned short)c[h2 * 4 + 2]);
                const float f3 = b2f((unsigned short)c[h2 * 4 + 3]);
                const bool m = f3 > -1.0e30f;
                lw[idx] = m ? (f0 * wg[0] + f1 * wg[1] + f2c * wg[2] + f3 * wg[3] + bg) : 0.f;
                e[idx]  = __expf(dv[idx] + f3);     // masked: exp(-inf) = 0
                se += e[idx];
            }
        }
        const float e32 = __expf(d32 + 1.0f);       // global token
        const float tot = se + __shfl_xor(se, 1) + e32;
        const float rinv = 1.0f / tot;
        const float add32 = (e32 * rinv + wg[3] + bg) * 0.03125f;

        #pragma unroll
        for (int pk = 0; pk < 4; ++pk) {
            f32x4 v;
            #pragma unroll
            for (int j = 0; j < 4; ++j) {
                int idx = pk * 4 + j;
                v[j] = e[idx] * rinv + lw[idx] + add32;
            }
            *(u16x4*)&kc[swz(r, half * 16 + pk * 4)] = pack4(v);
        }
    }

    // ---- Phase 3: x_out = V^T @ comb^T via MFMA (wave-private) ------------
    {
        bf16x8 av0 = *(const bf16x8*)&vt[swz(lm, ak)];
        bf16x8 av1 = *(const bf16x8*)&vt[swz(16 + lm, ak)];
        bf16x8 bc0 = *(const bf16x8*)&kc[swz(lm, ak)];
        bf16x8 bc1 = *(const bf16x8*)&kc[swz(16 + lm, ak)];
        f32x4 z = {0.f, 0.f, 0.f, 0.f};
        f32x4 x00 = __builtin_amdgcn_mfma_f32_16x16x32_bf16(av0, bc0, z, 0, 0, 0);
        f32x4 x10 = __builtin_amdgcn_mfma_f32_16x16x32_bf16(av1, bc0, z, 0, 0, 0);
        f32x4 x01 = __builtin_amdgcn_mfma_f32_16x16x32_bf16(av0, bc1, z, 0, 0, 0);
        f32x4 x11 = __builtin_amdgcn_mfma_f32_16x16x32_bf16(av1, bc1, z, 0, 0, 0);
        *(u16x4*)&qc[swz(lm, rb)]           = pack4(x00);
        *(u16x4*)&qc[swz(lm, 16 + rb)]      = pack4(x10);
        *(u16x4*)&qc[swz(16 + lm, rb)]      = pack4(x01);
        *(u16x4*)&qc[swz(16 + lm, 16 + rb)] = pack4(x11);
    }

    // ---- prefetch Wproj fragments + bias, then the cross-head barrier -----
    bf16x8 pw[2][4];
    float pb[2];
    #pragma unroll
    for (int t = 0; t < 2; ++t) {
        int col = w * 32 + t * 16 + lm;
        pb[t] = bproj[col];
        #pragma unroll
        for (int kk = 0; kk < 4; ++kk)
            pw[t][kk] = *(const bf16x8*)(wproj_b + col * CH + kk * 32 + ak);
    }
    __syncthreads();

    // ---- Phase 4: out = x_out @ Wproj^T + bproj ---------------------------
    {
        bf16x8 a2[2][4];
        #pragma unroll
        for (int kk = 0; kk < 4; ++kk) {
            a2[0][kk] = *(const bf16x8*)&Rq[kk * 1024 + swz(lm, ak)];
            a2[1][kk] = *(const bf16x8*)&Rq[kk * 1024 + swz(16 + lm, ak)];
        }
        float* ob = out + (size_t)b * BS * CH;
        #pragma unroll
        for (int t = 0; t < 2; ++t) {
            int col = w * 32 + t * 16 + lm;
            f32x4 acc0 = {pb[t], pb[t], pb[t], pb[t]};
            f32x4 acc1 = acc0;
            #pragma unroll
            for (int kk = 0; kk < 4; ++kk) {
                acc0 = __builtin_amdgcn_mfma_f32_16x16x32_bf16(a2[0][kk], pw[t][kk], acc0, 0, 0, 0);
                acc1 = __builtin_amdgcn_mfma_f32_16x16x32_bf16(a2[1][kk], pw[t][kk], acc1, 0, 0, 0);
            }
            #pragma unroll
            for (int j = 0; j < 4; ++j) {
                ob[(rb + j) * CH + col]      = acc0[j];
                ob[(16 + rb + j) * CH + col] = acc1[j];
            }
        }
    }
}

extern "C" void kernel_launch(void* const* d_in, const int* in_sizes, int n_in,
                              void* d_out, int out_size, void* d_ws, size_t ws_size,
                              hipStream_t stream) {
    const float* x          = (const float*)d_in[0];
    const float* edge_feats = (const float*)d_in[1];
    const float* Wqkv       = (const float*)d_in[2];
    const float* bqkv       = (const float*)d_in[3];
    const float* Wproj      = (const float*)d_in[4];
    const float* bproj      = (const float*)d_in[5];
    const float* Wgate      = (const float*)d_in[6];
    const float* bgate      = (const float*)d_in[7];
    const int*   attn_mask  = (const int*)d_in[8];
    float* out = (float*)d_out;
    short* wb  = (short*)d_ws;

    convert_weights<<<256, 256, 0, stream>>>(Wqkv, Wproj, wb);
    fused_block_attn<<<NBLK, 256, 0, stream>>>(
        x, edge_feats, bqkv, bproj, Wgate, bgate, attn_mask,
        wb, wb + 3 * CH * CH, out);
}

// Round 8
// 107.998 us; speedup vs baseline: 1.2853x; 1.0175x over previous
//
#include <hip/hip_runtime.h>
#include <hip/hip_bf16.h>

#define NBLK 4096
#define BS 32
#define CH 128

typedef float f32x4 __attribute__((ext_vector_type(4)));
typedef int   i32x4 __attribute__((ext_vector_type(4)));
typedef short bf16x8 __attribute__((ext_vector_type(8)));
typedef unsigned short u16x4 __attribute__((ext_vector_type(4)));

__device__ __forceinline__ short f2b(float x) {
    return __builtin_bit_cast(short, __float2bfloat16(x));
}
__device__ __forceinline__ float b2f(unsigned short h) {
    union { unsigned u; float f; } c; c.u = ((unsigned)h) << 16; return c.f;
}
__device__ __forceinline__ u16x4 pack4(f32x4 a) {
    u16x4 o;
    o[0] = (unsigned short)f2b(a[0]); o[1] = (unsigned short)f2b(a[1]);
    o[2] = (unsigned short)f2b(a[2]); o[3] = (unsigned short)f2b(a[3]);
    return o;
}
__device__ __forceinline__ bf16x8 pack8(f32x4 a, f32x4 b) {
    bf16x8 o;
    o[0] = f2b(a[0]); o[1] = f2b(a[1]); o[2] = f2b(a[2]); o[3] = f2b(a[3]);
    o[4] = f2b(b[0]); o[5] = f2b(b[1]); o[6] = f2b(b[2]); o[7] = f2b(b[3]);
    return o;
}
// swizzled index (shorts) within a [32 rows][32 cols] bf16 head-chunk (2KB)
__device__ __forceinline__ int swz(int row, int col) {
    return (row << 5) + ((((col >> 3) ^ ((row >> 1) & 3)) << 3) | (col & 7));
}

// --- pre-kernel: convert weights to bf16 into workspace -------------------
__global__ void convert_weights(const float* __restrict__ wqkv,
                                const float* __restrict__ wproj,
                                short* __restrict__ wsout) {
    int i = blockIdx.x * 256 + threadIdx.x;          // 0 .. 65535
    if (i < 3 * CH * CH) {
        wsout[i] = f2b(wqkv[i]);
    } else {
        int j = i - 3 * CH * CH;
        if (j < CH * CH) wsout[3 * CH * CH + j] = f2b(wproj[j]);
    }
}

// --- main fused kernel: one workgroup per 32-token block ------------------
// Wave w owns head w. Async-stage structure:
//   top:  ISSUE ef/mask HBM loads into registers (in flight through phase 1)
//   1:    QKV via MFMA (x + weights, L2-hot; weight frags hoisted)
//   st:   write ef (bf16, -inf mask sentinel) to efS LDS     [barrier]
//   2a:   scores^T via MFMA (wave-private)
//   2b:   softmax + gate (ef bf16 from LDS, sentinel mask)
//   3:    PV via MFMA (wave-private)                          [barrier]
//   4:    proj GEMM via MFMA
// LDS: 3x8192 (Rv,Rq,Rk) + efS 8192 = 32768 B.
__launch_bounds__(256, 3)
__global__ void fused_block_attn(
    const float* __restrict__ x,
    const float* __restrict__ edge_feats,
    const float* __restrict__ bqkv,
    const float* __restrict__ bproj,
    const float* __restrict__ wgate,
    const float* __restrict__ bgate,
    const int*   __restrict__ attn_mask,
    const short* __restrict__ wqkv_b,    // [384][128] bf16
    const short* __restrict__ wproj_b,   // [128][128] bf16
    float* __restrict__ out)
{
    const int b    = blockIdx.x;
    const int tid  = threadIdx.x;
    const int lane = tid & 63;
    const int w    = tid >> 6;
    const int lm   = lane & 15;
    const int g    = lane >> 4;
    const int ak   = g * 8;            // k-offset (elements) within K=32
    const int rb   = g * 4;            // D-row base within tile

    __shared__ short Rv[4096];
    __shared__ short Rq[4096];
    __shared__ short Rk[4096];
    __shared__ short efS[4096];        // bf16 ef: [r][chunk^(r&15)][8]
    short* vt = Rv + w * 1024;
    short* qc = Rq + w * 1024;
    short* kc = Rk + w * 1024;

    // ---- top: ISSUE the HBM ef/mask stream (consumed after phase 1) ------
    const int pr = tid >> 3;           // row 0..31
    const int pu = tid & 7;            // s-group; s = pu*4 .. pu*4+3
    const float* efp = edge_feats + ((size_t)(b * BS + pr) * 33 + pu * 4) * 4;
    f32x4 efv[4];
    efv[0] = ((const f32x4*)efp)[0];
    efv[1] = ((const f32x4*)efp)[1];
    efv[2] = ((const f32x4*)efp)[2];
    efv[3] = ((const f32x4*)efp)[3];
    const i32x4 mkv = *(const i32x4*)(attn_mask + (size_t)(b * BS + pr) * 33 + pu * 4);

    // ---- Phase 1: own-head QKV via MFMA (x + weights all L2-hot) ---------
    const float* xb = x + (size_t)b * (BS * CH);
    bf16x8 kvf[2][4];
    #pragma unroll
    for (int kk = 0; kk < 4; ++kk) {
        const float* p0 = xb + lm * CH + kk * 32 + ak;
        const float* p1 = p0 + 16 * CH;
        kvf[0][kk] = pack8(*(const f32x4*)p0, *(const f32x4*)(p0 + 4));
        kvf[1][kk] = pack8(*(const f32x4*)p1, *(const f32x4*)(p1 + 4));
    }

    // hoist all q/k weight fragments (4 tiles x 4 frags) before any MFMA
    bf16x8 wfa[4][4];
    #pragma unroll
    for (int t = 0; t < 4; ++t) {
        const int o0 = ((t >> 1) ? CH : 0) + w * 32 + (t & 1) * 16;
        const short* wp = wqkv_b + (o0 + lm) * CH + ak;
        #pragma unroll
        for (int kk = 0; kk < 4; ++kk) wfa[t][kk] = *(const bf16x8*)(wp + kk * 32);
    }
    #pragma unroll
    for (int t = 0; t < 4; ++t) {          // q0,q1,k0,k1 (swapped orient)
        const int o0 = ((t >> 1) ? CH : 0) + w * 32 + (t & 1) * 16;
        f32x4 acc0 = *(const f32x4*)(bqkv + o0 + rb);
        f32x4 acc1 = acc0;
        #pragma unroll
        for (int kk = 0; kk < 4; ++kk) {
            acc0 = __builtin_amdgcn_mfma_f32_16x16x32_bf16(wfa[t][kk], kvf[0][kk], acc0, 0, 0, 0);
            acc1 = __builtin_amdgcn_mfma_f32_16x16x32_bf16(wfa[t][kk], kvf[1][kk], acc1, 0, 0, 0);
        }
        short* dst = (t >> 1) ? kc : qc;
        const int c0 = (t & 1) * 16 + rb;
        *(u16x4*)&dst[swz(lm, c0)]      = pack4(acc0);
        *(u16x4*)&dst[swz(16 + lm, c0)] = pack4(acc1);
    }
    #pragma unroll
    for (int t = 0; t < 2; ++t) {          // v0,v1 (normal orient -> V^T)
        const int o0 = 2 * CH + w * 32 + t * 16;
        const short* wp = wqkv_b + (o0 + lm) * CH + ak;
        bf16x8 wf[4];
        #pragma unroll
        for (int kk = 0; kk < 4; ++kk) wf[kk] = *(const bf16x8*)(wp + kk * 32);
        float bv = bqkv[o0 + lm];
        f32x4 acc0 = {bv, bv, bv, bv};
        f32x4 acc1 = acc0;
        #pragma unroll
        for (int kk = 0; kk < 4; ++kk) {
            acc0 = __builtin_amdgcn_mfma_f32_16x16x32_bf16(kvf[0][kk], wf[kk], acc0, 0, 0, 0);
            acc1 = __builtin_amdgcn_mfma_f32_16x16x32_bf16(kvf[1][kk], wf[kk], acc1, 0, 0, 0);
        }
        const int row = t * 16 + lm;
        *(u16x4*)&vt[swz(row, rb)]      = pack4(acc0);
        *(u16x4*)&vt[swz(row, 16 + rb)] = pack4(acc1);
    }

    // ---- stage bf16 ef (loads long since returned); masked -> -inf -------
    {
        #pragma unroll
        for (int jj = 0; jj < 2; ++jj) {         // chunk = pu*2 + jj
            bf16x8 st;
            #pragma unroll
            for (int h2 = 0; h2 < 2; ++h2) {     // s within chunk
                const int s = pu * 4 + jj * 2 + h2;
                f32x4 e = efv[jj * 2 + h2];
                if (s == pr) { e[0] = 0.f; e[1] = 0.f; e[2] = 0.f; e[3] = 1.f; }
                const float e3 = mkv[jj * 2 + h2] ? e[3] : -INFINITY;
                st[h2 * 4 + 0] = f2b(e[0]);
                st[h2 * 4 + 1] = f2b(e[1]);
                st[h2 * 4 + 2] = f2b(e[2]);
                st[h2 * 4 + 3] = f2b(e3);
            }
            const int chunk = pu * 2 + jj;
            *(bf16x8*)&efS[pr * 128 + ((chunk ^ (pr & 15)) << 3)] = st;
        }
    }
    __syncthreads();

    // ---- Phase 2a: scores^T = K @ Q^T (wave-private) ----------------------
    {
        bf16x8 af0 = *(const bf16x8*)&kc[swz(lm, ak)];
        bf16x8 af1 = *(const bf16x8*)&kc[swz(16 + lm, ak)];
        bf16x8 bq0 = *(const bf16x8*)&qc[swz(lm, ak)];
        bf16x8 bq1 = *(const bf16x8*)&qc[swz(16 + lm, ak)];
        f32x4 z = {0.f, 0.f, 0.f, 0.f};
        f32x4 s00 = __builtin_amdgcn_mfma_f32_16x16x32_bf16(af0, bq0, z, 0, 0, 0);
        f32x4 s10 = __builtin_amdgcn_mfma_f32_16x16x32_bf16(af1, bq0, z, 0, 0, 0);
        f32x4 s01 = __builtin_amdgcn_mfma_f32_16x16x32_bf16(af0, bq1, z, 0, 0, 0);
        f32x4 s11 = __builtin_amdgcn_mfma_f32_16x16x32_bf16(af1, bq1, z, 0, 0, 0);
        const float SC = 0.17677669529663689f;
        *(u16x4*)&kc[swz(lm, rb)]           = pack4(s00 * SC);
        *(u16x4*)&kc[swz(lm, 16 + rb)]      = pack4(s10 * SC);
        *(u16x4*)&kc[swz(16 + lm, rb)]      = pack4(s01 * SC);
        *(u16x4*)&kc[swz(16 + lm, 16 + rb)] = pack4(s11 * SC);
    }

    // ---- Phase 2b: softmax + gate (ef bf16, sentinel-masked) --------------
    {
        const int r    = lane >> 1;
        const int half = lane & 1;
        bf16x8 t0 = *(const bf16x8*)&kc[swz(r, half * 16)];
        bf16x8 t1 = *(const bf16x8*)&kc[swz(r, half * 16 + 8)];

        float dv[16];
        #pragma unroll
        for (int j = 0; j < 8; ++j) {
            dv[j]     = b2f((unsigned short)t0[j]);
            dv[8 + j] = b2f((unsigned short)t1[j]);
        }
        float sd = 0.f;
        #pragma unroll
        for (int j = 0; j < 16; ++j) sd += dv[j];
        sd += __shfl_xor(sd, 1);
        const float d32 = sd * 0.03125f;

        f32x4 wg = *(const f32x4*)(wgate + w * 4);
        float bg = bgate[w];

        float e[16], lw[16];
        float se = 0.f;
        #pragma unroll
        for (int pk = 0; pk < 8; ++pk) {
            const int chunk = half * 8 + pk;
            bf16x8 c = *(const bf16x8*)&efS[r * 128 + ((chunk ^ (r & 15)) << 3)];
            #pragma unroll
            for (int h2 = 0; h2 < 2; ++h2) {
                const int idx = pk * 2 + h2;
                const float f0 = b2f((unsigned short)c[h2 * 4 + 0]);
                const float f1 = b2f((unsigned short)c[h2 * 4 + 1]);
                const float f2c = b2f((unsigned short)c[h2 * 4 + 2]);
                const float f3 = b2f((unsigned short)c[h2 * 4 + 3]);
                const bool m = f3 > -1.0e30f;
                lw[idx] = m ? (f0 * wg[0] + f1 * wg[1] + f2c * wg[2] + f3 * wg[3] + bg) : 0.f;
                e[idx]  = __expf(dv[idx] + f3);     // masked: exp(-inf) = 0
                se += e[idx];
            }
        }
        const float e32 = __expf(d32 + 1.0f);       // global token
        const float tot = se + __shfl_xor(se, 1) + e32;
        const float rinv = 1.0f / tot;
        const float add32 = (e32 * rinv + wg[3] + bg) * 0.03125f;

        #pragma unroll
        for (int pk = 0; pk < 4; ++pk) {
            f32x4 v;
            #pragma unroll
            for (int j = 0; j < 4; ++j) {
                int idx = pk * 4 + j;
                v[j] = e[idx] * rinv + lw[idx] + add32;
            }
            *(u16x4*)&kc[swz(r, half * 16 + pk * 4)] = pack4(v);
        }
    }

    // ---- Phase 3: x_out = V^T @ comb^T via MFMA (wave-private) ------------
    {
        bf16x8 av0 = *(const bf16x8*)&vt[swz(lm, ak)];
        bf16x8 av1 = *(const bf16x8*)&vt[swz(16 + lm, ak)];
        bf16x8 bc0 = *(const bf16x8*)&kc[swz(lm, ak)];
        bf16x8 bc1 = *(const bf16x8*)&kc[swz(16 + lm, ak)];
        f32x4 z = {0.f, 0.f, 0.f, 0.f};
        f32x4 x00 = __builtin_amdgcn_mfma_f32_16x16x32_bf16(av0, bc0, z, 0, 0, 0);
        f32x4 x10 = __builtin_amdgcn_mfma_f32_16x16x32_bf16(av1, bc0, z, 0, 0, 0);
        f32x4 x01 = __builtin_amdgcn_mfma_f32_16x16x32_bf16(av0, bc1, z, 0, 0, 0);
        f32x4 x11 = __builtin_amdgcn_mfma_f32_16x16x32_bf16(av1, bc1, z, 0, 0, 0);
        *(u16x4*)&qc[swz(lm, rb)]           = pack4(x00);
        *(u16x4*)&qc[swz(lm, 16 + rb)]      = pack4(x10);
        *(u16x4*)&qc[swz(16 + lm, rb)]      = pack4(x01);
        *(u16x4*)&qc[swz(16 + lm, 16 + rb)] = pack4(x11);
    }

    // ---- prefetch Wproj fragments + bias, then the cross-head barrier -----
    bf16x8 pw[2][4];
    float pb[2];
    #pragma unroll
    for (int t = 0; t < 2; ++t) {
        int col = w * 32 + t * 16 + lm;
        pb[t] = bproj[col];
        #pragma unroll
        for (int kk = 0; kk < 4; ++kk)
            pw[t][kk] = *(const bf16x8*)(wproj_b + col * CH + kk * 32 + ak);
    }
    __syncthreads();

    // ---- Phase 4: out = x_out @ Wproj^T + bproj ---------------------------
    {
        bf16x8 a2[2][4];
        #pragma unroll
        for (int kk = 0; kk < 4; ++kk) {
            a2[0][kk] = *(const bf16x8*)&Rq[kk * 1024 + swz(lm, ak)];
            a2[1][kk] = *(const bf16x8*)&Rq[kk * 1024 + swz(16 + lm, ak)];
        }
        float* ob = out + (size_t)b * BS * CH;
        #pragma unroll
        for (int t = 0; t < 2; ++t) {
            int col = w * 32 + t * 16 + lm;
            f32x4 acc0 = {pb[t], pb[t], pb[t], pb[t]};
            f32x4 acc1 = acc0;
            #pragma unroll
            for (int kk = 0; kk < 4; ++kk) {
                acc0 = __builtin_amdgcn_mfma_f32_16x16x32_bf16(a2[0][kk], pw[t][kk], acc0, 0, 0, 0);
                acc1 = __builtin_amdgcn_mfma_f32_16x16x32_bf16(a2[1][kk], pw[t][kk], acc1, 0, 0, 0);
            }
            #pragma unroll
            for (int j = 0; j < 4; ++j) {
                ob[(rb + j) * CH + col]      = acc0[j];
                ob[(16 + rb + j) * CH + col] = acc1[j];
            }
        }
    }
}

extern "C" void kernel_launch(void* const* d_in, const int* in_sizes, int n_in,
                              void* d_out, int out_size, void* d_ws, size_t ws_size,
                              hipStream_t stream) {
    const float* x          = (const float*)d_in[0];
    const float* edge_feats = (const float*)d_in[1];
    const float* Wqkv       = (const float*)d_in[2];
    const float* bqkv       = (const float*)d_in[3];
    const float* Wproj      = (const float*)d_in[4];
    const float* bproj      = (const float*)d_in[5];
    const float* Wgate      = (const float*)d_in[6];
    const float* bgate      = (const float*)d_in[7];
    const int*   attn_mask  = (const int*)d_in[8];
    float* out = (float*)d_out;
    short* wb  = (short*)d_ws;

    convert_weights<<<256, 256, 0, stream>>>(Wqkv, Wproj, wb);
    fused_block_attn<<<NBLK, 256, 0, stream>>>(
        x, edge_feats, bqkv, bproj, Wgate, bgate, attn_mask,
        wb, wb + 3 * CH * CH, out);
}

// Round 9
// 107.810 us; speedup vs baseline: 1.2875x; 1.0017x over previous
//
#include <hip/hip_runtime.h>
#include <hip/hip_bf16.h>

#define NBLK 4096
#define BS 32
#define CH 128

typedef float f32x4 __attribute__((ext_vector_type(4)));
typedef int   i32x4 __attribute__((ext_vector_type(4)));
typedef short bf16x8 __attribute__((ext_vector_type(8)));
typedef unsigned short u16x4 __attribute__((ext_vector_type(4)));

__device__ __forceinline__ short f2b(float x) {
    return __builtin_bit_cast(short, __float2bfloat16(x));
}
__device__ __forceinline__ float b2f(unsigned short h) {
    union { unsigned u; float f; } c; c.u = ((unsigned)h) << 16; return c.f;
}
__device__ __forceinline__ u16x4 pack4(f32x4 a) {
    u16x4 o;
    o[0] = (unsigned short)f2b(a[0]); o[1] = (unsigned short)f2b(a[1]);
    o[2] = (unsigned short)f2b(a[2]); o[3] = (unsigned short)f2b(a[3]);
    return o;
}
__device__ __forceinline__ bf16x8 pack8(f32x4 a, f32x4 b) {
    bf16x8 o;
    o[0] = f2b(a[0]); o[1] = f2b(a[1]); o[2] = f2b(a[2]); o[3] = f2b(a[3]);
    o[4] = f2b(b[0]); o[5] = f2b(b[1]); o[6] = f2b(b[2]); o[7] = f2b(b[3]);
    return o;
}
// swizzled index (shorts) within a [32 rows][32 cols] bf16 head-chunk (2KB)
__device__ __forceinline__ int swz(int row, int col) {
    return (row << 5) + ((((col >> 3) ^ ((row >> 1) & 3)) << 3) | (col & 7));
}

// --- pre-kernel: convert weights to bf16 into workspace -------------------
__global__ void convert_weights(const float* __restrict__ wqkv,
                                const float* __restrict__ wproj,
                                short* __restrict__ wsout) {
    int i = blockIdx.x * 256 + threadIdx.x;          // 0 .. 65535
    if (i < 3 * CH * CH) {
        wsout[i] = f2b(wqkv[i]);
    } else {
        int j = i - 3 * CH * CH;
        if (j < CH * CH) wsout[3 * CH * CH + j] = f2b(wproj[j]);
    }
}

// --- main fused kernel: one workgroup per 32-token block ------------------
// Wave w owns head w. Async-stage structure:
//   top:  ISSUE ef/mask HBM loads into registers (in flight through phase 1)
//   1:    QKV via MFMA (x + weights, L2-hot; weight frags hoisted)
//   st:   write ef (bf16, -inf mask sentinel) to efS LDS     [barrier]
//   2a:   scores^T via MFMA (wave-private)
//   2b:   softmax + gate (ef bf16 from LDS, sentinel mask)
//   3:    PV via MFMA (wave-private)                          [barrier]
//   4:    proj GEMM via MFMA
// LDS: 3x8192 (Rv,Rq,Rk) + efS 8192 = 32768 B.
__launch_bounds__(256, 3)
__global__ void fused_block_attn(
    const float* __restrict__ x,
    const float* __restrict__ edge_feats,
    const float* __restrict__ bqkv,
    const float* __restrict__ bproj,
    const float* __restrict__ wgate,
    const float* __restrict__ bgate,
    const int*   __restrict__ attn_mask,
    const short* __restrict__ wqkv_b,    // [384][128] bf16
    const short* __restrict__ wproj_b,   // [128][128] bf16
    float* __restrict__ out)
{
    const int b    = blockIdx.x;
    const int tid  = threadIdx.x;
    const int lane = tid & 63;
    const int w    = tid >> 6;
    const int lm   = lane & 15;
    const int g    = lane >> 4;
    const int ak   = g * 8;            // k-offset (elements) within K=32
    const int rb   = g * 4;            // D-row base within tile

    __shared__ short Rv[4096];
    __shared__ short Rq[4096];
    __shared__ short Rk[4096];
    __shared__ short efS[4096];        // bf16 ef: [r][chunk^(r&15)][8]
    short* vt = Rv + w * 1024;
    short* qc = Rq + w * 1024;
    short* kc = Rk + w * 1024;

    // ---- top: ISSUE the HBM ef/mask stream (consumed after phase 1) ------
    const int pr = tid >> 3;           // row 0..31
    const int pu = tid & 7;            // s-group; s = pu*4 .. pu*4+3
    const float* efp = edge_feats + ((size_t)(b * BS + pr) * 33 + pu * 4) * 4;
    f32x4 efv[4];
    efv[0] = ((const f32x4*)efp)[0];
    efv[1] = ((const f32x4*)efp)[1];
    efv[2] = ((const f32x4*)efp)[2];
    efv[3] = ((const f32x4*)efp)[3];
    const i32x4 mkv = *(const i32x4*)(attn_mask + (size_t)(b * BS + pr) * 33 + pu * 4);

    // ---- Phase 1: own-head QKV via MFMA (x + weights all L2-hot) ---------
    const float* xb = x + (size_t)b * (BS * CH);
    bf16x8 kvf[2][4];
    #pragma unroll
    for (int kk = 0; kk < 4; ++kk) {
        const float* p0 = xb + lm * CH + kk * 32 + ak;
        const float* p1 = p0 + 16 * CH;
        kvf[0][kk] = pack8(*(const f32x4*)p0, *(const f32x4*)(p0 + 4));
        kvf[1][kk] = pack8(*(const f32x4*)p1, *(const f32x4*)(p1 + 4));
    }

    // hoist all q/k weight fragments (4 tiles x 4 frags) before any MFMA
    bf16x8 wfa[4][4];
    #pragma unroll
    for (int t = 0; t < 4; ++t) {
        const int o0 = ((t >> 1) ? CH : 0) + w * 32 + (t & 1) * 16;
        const short* wp = wqkv_b + (o0 + lm) * CH + ak;
        #pragma unroll
        for (int kk = 0; kk < 4; ++kk) wfa[t][kk] = *(const bf16x8*)(wp + kk * 32);
    }
    #pragma unroll
    for (int t = 0; t < 4; ++t) {          // q0,q1,k0,k1 (swapped orient)
        const int o0 = ((t >> 1) ? CH : 0) + w * 32 + (t & 1) * 16;
        f32x4 acc0 = *(const f32x4*)(bqkv + o0 + rb);
        f32x4 acc1 = acc0;
        #pragma unroll
        for (int kk = 0; kk < 4; ++kk) {
            acc0 = __builtin_amdgcn_mfma_f32_16x16x32_bf16(wfa[t][kk], kvf[0][kk], acc0, 0, 0, 0);
            acc1 = __builtin_amdgcn_mfma_f32_16x16x32_bf16(wfa[t][kk], kvf[1][kk], acc1, 0, 0, 0);
        }
        short* dst = (t >> 1) ? kc : qc;
        const int c0 = (t & 1) * 16 + rb;
        *(u16x4*)&dst[swz(lm, c0)]      = pack4(acc0);
        *(u16x4*)&dst[swz(16 + lm, c0)] = pack4(acc1);
    }
    #pragma unroll
    for (int t = 0; t < 2; ++t) {          // v0,v1 (normal orient -> V^T)
        const int o0 = 2 * CH + w * 32 + t * 16;
        const short* wp = wqkv_b + (o0 + lm) * CH + ak;
        bf16x8 wf[4];
        #pragma unroll
        for (int kk = 0; kk < 4; ++kk) wf[kk] = *(const bf16x8*)(wp + kk * 32);
        float bv = bqkv[o0 + lm];
        f32x4 acc0 = {bv, bv, bv, bv};
        f32x4 acc1 = acc0;
        #pragma unroll
        for (int kk = 0; kk < 4; ++kk) {
            acc0 = __builtin_amdgcn_mfma_f32_16x16x32_bf16(kvf[0][kk], wf[kk], acc0, 0, 0, 0);
            acc1 = __builtin_amdgcn_mfma_f32_16x16x32_bf16(kvf[1][kk], wf[kk], acc1, 0, 0, 0);
        }
        const int row = t * 16 + lm;
        *(u16x4*)&vt[swz(row, rb)]      = pack4(acc0);
        *(u16x4*)&vt[swz(row, 16 + rb)] = pack4(acc1);
    }

    // ---- stage bf16 ef (loads long since returned); masked -> -inf -------
    {
        #pragma unroll
        for (int jj = 0; jj < 2; ++jj) {         // chunk = pu*2 + jj
            bf16x8 st;
            #pragma unroll
            for (int h2 = 0; h2 < 2; ++h2) {     // s within chunk
                const int s = pu * 4 + jj * 2 + h2;
                f32x4 e = efv[jj * 2 + h2];
                if (s == pr) { e[0] = 0.f; e[1] = 0.f; e[2] = 0.f; e[3] = 1.f; }
                const float e3 = mkv[jj * 2 + h2] ? e[3] : -INFINITY;
                st[h2 * 4 + 0] = f2b(e[0]);
                st[h2 * 4 + 1] = f2b(e[1]);
                st[h2 * 4 + 2] = f2b(e[2]);
                st[h2 * 4 + 3] = f2b(e3);
            }
            const int chunk = pu * 2 + jj;
            *(bf16x8*)&efS[pr * 128 + ((chunk ^ (pr & 15)) << 3)] = st;
        }
    }
    __syncthreads();

    // ---- Phase 2a: scores^T = K @ Q^T (wave-private) ----------------------
    {
        bf16x8 af0 = *(const bf16x8*)&kc[swz(lm, ak)];
        bf16x8 af1 = *(const bf16x8*)&kc[swz(16 + lm, ak)];
        bf16x8 bq0 = *(const bf16x8*)&qc[swz(lm, ak)];
        bf16x8 bq1 = *(const bf16x8*)&qc[swz(16 + lm, ak)];
        f32x4 z = {0.f, 0.f, 0.f, 0.f};
        f32x4 s00 = __builtin_amdgcn_mfma_f32_16x16x32_bf16(af0, bq0, z, 0, 0, 0);
        f32x4 s10 = __builtin_amdgcn_mfma_f32_16x16x32_bf16(af1, bq0, z, 0, 0, 0);
        f32x4 s01 = __builtin_amdgcn_mfma_f32_16x16x32_bf16(af0, bq1, z, 0, 0, 0);
        f32x4 s11 = __builtin_amdgcn_mfma_f32_16x16x32_bf16(af1, bq1, z, 0, 0, 0);
        const float SC = 0.17677669529663689f;
        *(u16x4*)&kc[swz(lm, rb)]           = pack4(s00 * SC);
        *(u16x4*)&kc[swz(lm, 16 + rb)]      = pack4(s10 * SC);
        *(u16x4*)&kc[swz(16 + lm, rb)]      = pack4(s01 * SC);
        *(u16x4*)&kc[swz(16 + lm, 16 + rb)] = pack4(s11 * SC);
    }

    // ---- Phase 2b: softmax + gate (ef bf16, sentinel-masked) --------------
    {
        const int r    = lane >> 1;
        const int half = lane & 1;
        bf16x8 t0 = *(const bf16x8*)&kc[swz(r, half * 16)];
        bf16x8 t1 = *(const bf16x8*)&kc[swz(r, half * 16 + 8)];

        float dv[16];
        #pragma unroll
        for (int j = 0; j < 8; ++j) {
            dv[j]     = b2f((unsigned short)t0[j]);
            dv[8 + j] = b2f((unsigned short)t1[j]);
        }
        float sd = 0.f;
        #pragma unroll
        for (int j = 0; j < 16; ++j) sd += dv[j];
        sd += __shfl_xor(sd, 1);
        const float d32 = sd * 0.03125f;

        f32x4 wg = *(const f32x4*)(wgate + w * 4);
        float bg = bgate[w];

        float e[16], lw[16];
        float se = 0.f;
        #pragma unroll
        for (int pk = 0; pk < 8; ++pk) {
            const int chunk = half * 8 + pk;
            bf16x8 c = *(const bf16x8*)&efS[r * 128 + ((chunk ^ (r & 15)) << 3)];
            #pragma unroll
            for (int h2 = 0; h2 < 2; ++h2) {
                const int idx = pk * 2 + h2;
                const float f0 = b2f((unsigned short)c[h2 * 4 + 0]);
                const float f1 = b2f((unsigned short)c[h2 * 4 + 1]);
                const float f2c = b2f((unsigned short)c[h2 * 4 + 2]);
                const float f3 = b2f((unsigned short)c[h2 * 4 + 3]);
                const bool m = f3 > -1.0e30f;
                lw[idx] = m ? (f0 * wg[0] + f1 * wg[1] + f2c * wg[2] + f3 * wg[3] + bg) : 0.f;
                e[idx]  = __expf(dv[idx] + f3);     // masked: exp(-inf) = 0
                se += e[idx];
            }
        }
        const float e32 = __expf(d32 + 1.0f);       // global token
        const float tot = se + __shfl_xor(se, 1) + e32;
        const float rinv = 1.0f / tot;
        const float add32 = (e32 * rinv + wg[3] + bg) * 0.03125f;

        #pragma unroll
        for (int pk = 0; pk < 4; ++pk) {
            f32x4 v;
            #pragma unroll
            for (int j = 0; j < 4; ++j) {
                int idx = pk * 4 + j;
                v[j] = e[idx] * rinv + lw[idx] + add32;
            }
            *(u16x4*)&kc[swz(r, half * 16 + pk * 4)] = pack4(v);
        }
    }

    // ---- Phase 3: x_out = V^T @ comb^T via MFMA (wave-private) ------------
    {
        bf16x8 av0 = *(const bf16x8*)&vt[swz(lm, ak)];
        bf16x8 av1 = *(const bf16x8*)&vt[swz(16 + lm, ak)];
        bf16x8 bc0 = *(const bf16x8*)&kc[swz(lm, ak)];
        bf16x8 bc1 = *(const bf16x8*)&kc[swz(16 + lm, ak)];
        f32x4 z = {0.f, 0.f, 0.f, 0.f};
        f32x4 x00 = __builtin_amdgcn_mfma_f32_16x16x32_bf16(av0, bc0, z, 0, 0, 0);
        f32x4 x10 = __builtin_amdgcn_mfma_f32_16x16x32_bf16(av1, bc0, z, 0, 0, 0);
        f32x4 x01 = __builtin_amdgcn_mfma_f32_16x16x32_bf16(av0, bc1, z, 0, 0, 0);
        f32x4 x11 = __builtin_amdgcn_mfma_f32_16x16x32_bf16(av1, bc1, z, 0, 0, 0);
        *(u16x4*)&qc[swz(lm, rb)]           = pack4(x00);
        *(u16x4*)&qc[swz(lm, 16 + rb)]      = pack4(x10);
        *(u16x4*)&qc[swz(16 + lm, rb)]      = pack4(x01);
        *(u16x4*)&qc[swz(16 + lm, 16 + rb)] = pack4(x11);
    }

    // ---- prefetch Wproj fragments + bias, then the cross-head barrier -----
    bf16x8 pw[2][4];
    float pb[2];
    #pragma unroll
    for (int t = 0; t < 2; ++t) {
        int col = w * 32 + t * 16 + lm;
        pb[t] = bproj[col];
        #pragma unroll
        for (int kk = 0; kk < 4; ++kk)
            pw[t][kk] = *(const bf16x8*)(wproj_b + col * CH + kk * 32 + ak);
    }
    __syncthreads();

    // ---- Phase 4: out = x_out @ Wproj^T + bproj ---------------------------
    {
        bf16x8 a2[2][4];
        #pragma unroll
        for (int kk = 0; kk < 4; ++kk) {
            a2[0][kk] = *(const bf16x8*)&Rq[kk * 1024 + swz(lm, ak)];
            a2[1][kk] = *(const bf16x8*)&Rq[kk * 1024 + swz(16 + lm, ak)];
        }
        float* ob = out + (size_t)b * BS * CH;
        #pragma unroll
        for (int t = 0; t < 2; ++t) {
            int col = w * 32 + t * 16 + lm;
            f32x4 acc0 = {pb[t], pb[t], pb[t], pb[t]};
            f32x4 acc1 = acc0;
            #pragma unroll
            for (int kk = 0; kk < 4; ++kk) {
                acc0 = __builtin_amdgcn_mfma_f32_16x16x32_bf16(a2[0][kk], pw[t][kk], acc0, 0, 0, 0);
                acc1 = __builtin_amdgcn_mfma_f32_16x16x32_bf16(a2[1][kk], pw[t][kk], acc1, 0, 0, 0);
            }
            #pragma unroll
            for (int j = 0; j < 4; ++j) {
                ob[(rb + j) * CH + col]      = acc0[j];
                ob[(16 + rb + j) * CH + col] = acc1[j];
            }
        }
    }
}

extern "C" void kernel_launch(void* const* d_in, const int* in_sizes, int n_in,
                              void* d_out, int out_size, void* d_ws, size_t ws_size,
                              hipStream_t stream) {
    const float* x          = (const float*)d_in[0];
    const float* edge_feats = (const float*)d_in[1];
    const float* Wqkv       = (const float*)d_in[2];
    const float* bqkv       = (const float*)d_in[3];
    const float* Wproj      = (const float*)d_in[4];
    const float* bproj      = (const float*)d_in[5];
    const float* Wgate      = (const float*)d_in[6];
    const float* bgate      = (const float*)d_in[7];
    const int*   attn_mask  = (const int*)d_in[8];
    float* out = (float*)d_out;
    short* wb  = (short*)d_ws;

    convert_weights<<<256, 256, 0, stream>>>(Wqkv, Wproj, wb);
    fused_block_attn<<<NBLK, 256, 0, stream>>>(
        x, edge_feats, bqkv, bproj, Wgate, bgate, attn_mask,
        wb, wb + 3 * CH * CH, out);
}

// Round 10
// 107.784 us; speedup vs baseline: 1.2879x; 1.0002x over previous
//
#include <hip/hip_runtime.h>
#include <hip/hip_bf16.h>

#define NBLK 4096
#define BS 32
#define CH 128

typedef float f32x4 __attribute__((ext_vector_type(4)));
typedef int   i32x4 __attribute__((ext_vector_type(4)));
typedef short bf16x8 __attribute__((ext_vector_type(8)));
typedef unsigned short u16x4 __attribute__((ext_vector_type(4)));

__device__ __forceinline__ short f2b(float x) {
    return __builtin_bit_cast(short, __float2bfloat16(x));
}
__device__ __forceinline__ float b2f(unsigned short h) {
    union { unsigned u; float f; } c; c.u = ((unsigned)h) << 16; return c.f;
}
__device__ __forceinline__ u16x4 pack4(f32x4 a) {
    u16x4 o;
    o[0] = (unsigned short)f2b(a[0]); o[1] = (unsigned short)f2b(a[1]);
    o[2] = (unsigned short)f2b(a[2]); o[3] = (unsigned short)f2b(a[3]);
    return o;
}
__device__ __forceinline__ bf16x8 pack8(f32x4 a, f32x4 b) {
    bf16x8 o;
    o[0] = f2b(a[0]); o[1] = f2b(a[1]); o[2] = f2b(a[2]); o[3] = f2b(a[3]);
    o[4] = f2b(b[0]); o[5] = f2b(b[1]); o[6] = f2b(b[2]); o[7] = f2b(b[3]);
    return o;
}
// swizzled index (shorts) within a [32 rows][32 cols] bf16 head-chunk (2KB)
__device__ __forceinline__ int swz(int row, int col) {
    return (row << 5) + ((((col >> 3) ^ ((row >> 1) & 3)) << 3) | (col & 7));
}

// --- pre-kernel: convert weights to bf16 into workspace -------------------
__global__ void convert_weights(const float* __restrict__ wqkv,
                                const float* __restrict__ wproj,
                                short* __restrict__ wsout) {
    int i = blockIdx.x * 256 + threadIdx.x;          // 0 .. 65535
    if (i < 3 * CH * CH) {
        wsout[i] = f2b(wqkv[i]);
    } else {
        int j = i - 3 * CH * CH;
        if (j < CH * CH) wsout[3 * CH * CH + j] = f2b(wproj[j]);
    }
}

// --- main fused kernel: one workgroup per 32-token block ------------------
// Wave w owns head w. Async-stage structure:
//   top:  ISSUE ef/mask HBM loads into registers (in flight through phase 1)
//   1:    QKV via MFMA (x + weights, L2-hot; weight frags hoisted)
//   st:   write ef (bf16, -inf mask sentinel) to efS LDS     [barrier]
//   2a:   scores^T via MFMA (wave-private)
//   2b:   softmax + gate (ef bf16 from LDS, sentinel mask)
//   3:    PV via MFMA (wave-private)                          [barrier]
//   4:    proj GEMM via MFMA
// LDS: 3x8192 (Rv,Rq,Rk) + efS 8192 = 32768 B.
__launch_bounds__(256, 3)
__global__ void fused_block_attn(
    const float* __restrict__ x,
    const float* __restrict__ edge_feats,
    const float* __restrict__ bqkv,
    const float* __restrict__ bproj,
    const float* __restrict__ wgate,
    const float* __restrict__ bgate,
    const int*   __restrict__ attn_mask,
    const short* __restrict__ wqkv_b,    // [384][128] bf16
    const short* __restrict__ wproj_b,   // [128][128] bf16
    float* __restrict__ out)
{
    const int b    = blockIdx.x;
    const int tid  = threadIdx.x;
    const int lane = tid & 63;
    const int w    = tid >> 6;
    const int lm   = lane & 15;
    const int g    = lane >> 4;
    const int ak   = g * 8;            // k-offset (elements) within K=32
    const int rb   = g * 4;            // D-row base within tile

    __shared__ short Rv[4096];
    __shared__ short Rq[4096];
    __shared__ short Rk[4096];
    __shared__ short efS[4096];        // bf16 ef: [r][chunk^(r&15)][8]
    short* vt = Rv + w * 1024;
    short* qc = Rq + w * 1024;
    short* kc = Rk + w * 1024;

    // ---- top: ISSUE the HBM ef/mask stream (consumed after phase 1) ------
    const int pr = tid >> 3;           // row 0..31
    const int pu = tid & 7;            // s-group; s = pu*4 .. pu*4+3
    const float* efp = edge_feats + ((size_t)(b * BS + pr) * 33 + pu * 4) * 4;
    f32x4 efv[4];
    efv[0] = ((const f32x4*)efp)[0];
    efv[1] = ((const f32x4*)efp)[1];
    efv[2] = ((const f32x4*)efp)[2];
    efv[3] = ((const f32x4*)efp)[3];
    const i32x4 mkv = *(const i32x4*)(attn_mask + (size_t)(b * BS + pr) * 33 + pu * 4);

    // ---- Phase 1: own-head QKV via MFMA (x + weights all L2-hot) ---------
    const float* xb = x + (size_t)b * (BS * CH);
    bf16x8 kvf[2][4];
    #pragma unroll
    for (int kk = 0; kk < 4; ++kk) {
        const float* p0 = xb + lm * CH + kk * 32 + ak;
        const float* p1 = p0 + 16 * CH;
        kvf[0][kk] = pack8(*(const f32x4*)p0, *(const f32x4*)(p0 + 4));
        kvf[1][kk] = pack8(*(const f32x4*)p1, *(const f32x4*)(p1 + 4));
    }

    // hoist all q/k weight fragments (4 tiles x 4 frags) before any MFMA
    bf16x8 wfa[4][4];
    #pragma unroll
    for (int t = 0; t < 4; ++t) {
        const int o0 = ((t >> 1) ? CH : 0) + w * 32 + (t & 1) * 16;
        const short* wp = wqkv_b + (o0 + lm) * CH + ak;
        #pragma unroll
        for (int kk = 0; kk < 4; ++kk) wfa[t][kk] = *(const bf16x8*)(wp + kk * 32);
    }
    #pragma unroll
    for (int t = 0; t < 4; ++t) {          // q0,q1,k0,k1 (swapped orient)
        const int o0 = ((t >> 1) ? CH : 0) + w * 32 + (t & 1) * 16;
        f32x4 acc0 = *(const f32x4*)(bqkv + o0 + rb);
        f32x4 acc1 = acc0;
        #pragma unroll
        for (int kk = 0; kk < 4; ++kk) {
            acc0 = __builtin_amdgcn_mfma_f32_16x16x32_bf16(wfa[t][kk], kvf[0][kk], acc0, 0, 0, 0);
            acc1 = __builtin_amdgcn_mfma_f32_16x16x32_bf16(wfa[t][kk], kvf[1][kk], acc1, 0, 0, 0);
        }
        short* dst = (t >> 1) ? kc : qc;
        const int c0 = (t & 1) * 16 + rb;
        *(u16x4*)&dst[swz(lm, c0)]      = pack4(acc0);
        *(u16x4*)&dst[swz(16 + lm, c0)] = pack4(acc1);
    }
    #pragma unroll
    for (int t = 0; t < 2; ++t) {          // v0,v1 (normal orient -> V^T)
        const int o0 = 2 * CH + w * 32 + t * 16;
        const short* wp = wqkv_b + (o0 + lm) * CH + ak;
        bf16x8 wf[4];
        #pragma unroll
        for (int kk = 0; kk < 4; ++kk) wf[kk] = *(const bf16x8*)(wp + kk * 32);
        float bv = bqkv[o0 + lm];
        f32x4 acc0 = {bv, bv, bv, bv};
        f32x4 acc1 = acc0;
        #pragma unroll
        for (int kk = 0; kk < 4; ++kk) {
            acc0 = __builtin_amdgcn_mfma_f32_16x16x32_bf16(kvf[0][kk], wf[kk], acc0, 0, 0, 0);
            acc1 = __builtin_amdgcn_mfma_f32_16x16x32_bf16(kvf[1][kk], wf[kk], acc1, 0, 0, 0);
        }
        const int row = t * 16 + lm;
        *(u16x4*)&vt[swz(row, rb)]      = pack4(acc0);
        *(u16x4*)&vt[swz(row, 16 + rb)] = pack4(acc1);
    }

    // ---- stage bf16 ef (loads long since returned); masked -> -inf -------
    {
        #pragma unroll
        for (int jj = 0; jj < 2; ++jj) {         // chunk = pu*2 + jj
            bf16x8 st;
            #pragma unroll
            for (int h2 = 0; h2 < 2; ++h2) {     // s within chunk
                const int s = pu * 4 + jj * 2 + h2;
                f32x4 e = efv[jj * 2 + h2];
                if (s == pr) { e[0] = 0.f; e[1] = 0.f; e[2] = 0.f; e[3] = 1.f; }
                const float e3 = mkv[jj * 2 + h2] ? e[3] : -INFINITY;
                st[h2 * 4 + 0] = f2b(e[0]);
                st[h2 * 4 + 1] = f2b(e[1]);
                st[h2 * 4 + 2] = f2b(e[2]);
                st[h2 * 4 + 3] = f2b(e3);
            }
            const int chunk = pu * 2 + jj;
            *(bf16x8*)&efS[pr * 128 + ((chunk ^ (pr & 15)) << 3)] = st;
        }
    }
    __syncthreads();

    // ---- Phase 2a: scores^T = K @ Q^T (wave-private) ----------------------
    {
        bf16x8 af0 = *(const bf16x8*)&kc[swz(lm, ak)];
        bf16x8 af1 = *(const bf16x8*)&kc[swz(16 + lm, ak)];
        bf16x8 bq0 = *(const bf16x8*)&qc[swz(lm, ak)];
        bf16x8 bq1 = *(const bf16x8*)&qc[swz(16 + lm, ak)];
        f32x4 z = {0.f, 0.f, 0.f, 0.f};
        f32x4 s00 = __builtin_amdgcn_mfma_f32_16x16x32_bf16(af0, bq0, z, 0, 0, 0);
        f32x4 s10 = __builtin_amdgcn_mfma_f32_16x16x32_bf16(af1, bq0, z, 0, 0, 0);
        f32x4 s01 = __builtin_amdgcn_mfma_f32_16x16x32_bf16(af0, bq1, z, 0, 0, 0);
        f32x4 s11 = __builtin_amdgcn_mfma_f32_16x16x32_bf16(af1, bq1, z, 0, 0, 0);
        const float SC = 0.17677669529663689f;
        *(u16x4*)&kc[swz(lm, rb)]           = pack4(s00 * SC);
        *(u16x4*)&kc[swz(lm, 16 + rb)]      = pack4(s10 * SC);
        *(u16x4*)&kc[swz(16 + lm, rb)]      = pack4(s01 * SC);
        *(u16x4*)&kc[swz(16 + lm, 16 + rb)] = pack4(s11 * SC);
    }

    // ---- Phase 2b: softmax + gate (ef bf16, sentinel-masked) --------------
    {
        const int r    = lane >> 1;
        const int half = lane & 1;
        bf16x8 t0 = *(const bf16x8*)&kc[swz(r, half * 16)];
        bf16x8 t1 = *(const bf16x8*)&kc[swz(r, half * 16 + 8)];

        float dv[16];
        #pragma unroll
        for (int j = 0; j < 8; ++j) {
            dv[j]     = b2f((unsigned short)t0[j]);
            dv[8 + j] = b2f((unsigned short)t1[j]);
        }
        float sd = 0.f;
        #pragma unroll
        for (int j = 0; j < 16; ++j) sd += dv[j];
        sd += __shfl_xor(sd, 1);
        const float d32 = sd * 0.03125f;

        f32x4 wg = *(const f32x4*)(wgate + w * 4);
        float bg = bgate[w];

        float e[16], lw[16];
        float se = 0.f;
        #pragma unroll
        for (int pk = 0; pk < 8; ++pk) {
            const int chunk = half * 8 + pk;
            bf16x8 c = *(const bf16x8*)&efS[r * 128 + ((chunk ^ (r & 15)) << 3)];
            #pragma unroll
            for (int h2 = 0; h2 < 2; ++h2) {
                const int idx = pk * 2 + h2;
                const float f0 = b2f((unsigned short)c[h2 * 4 + 0]);
                const float f1 = b2f((unsigned short)c[h2 * 4 + 1]);
                const float f2c = b2f((unsigned short)c[h2 * 4 + 2]);
                const float f3 = b2f((unsigned short)c[h2 * 4 + 3]);
                const bool m = f3 > -1.0e30f;
                lw[idx] = m ? (f0 * wg[0] + f1 * wg[1] + f2c * wg[2] + f3 * wg[3] + bg) : 0.f;
                e[idx]  = __expf(dv[idx] + f3);     // masked: exp(-inf) = 0
                se += e[idx];
            }
        }
        const float e32 = __expf(d32 + 1.0f);       // global token
        const float tot = se + __shfl_xor(se, 1) + e32;
        const float rinv = 1.0f / tot;
        const float add32 = (e32 * rinv + wg[3] + bg) * 0.03125f;

        #pragma unroll
        for (int pk = 0; pk < 4; ++pk) {
            f32x4 v;
            #pragma unroll
            for (int j = 0; j < 4; ++j) {
                int idx = pk * 4 + j;
                v[j] = e[idx] * rinv + lw[idx] + add32;
            }
            *(u16x4*)&kc[swz(r, half * 16 + pk * 4)] = pack4(v);
        }
    }

    // ---- Phase 3: x_out = V^T @ comb^T via MFMA (wave-private) ------------
    {
        bf16x8 av0 = *(const bf16x8*)&vt[swz(lm, ak)];
        bf16x8 av1 = *(const bf16x8*)&vt[swz(16 + lm, ak)];
        bf16x8 bc0 = *(const bf16x8*)&kc[swz(lm, ak)];
        bf16x8 bc1 = *(const bf16x8*)&kc[swz(16 + lm, ak)];
        f32x4 z = {0.f, 0.f, 0.f, 0.f};
        f32x4 x00 = __builtin_amdgcn_mfma_f32_16x16x32_bf16(av0, bc0, z, 0, 0, 0);
        f32x4 x10 = __builtin_amdgcn_mfma_f32_16x16x32_bf16(av1, bc0, z, 0, 0, 0);
        f32x4 x01 = __builtin_amdgcn_mfma_f32_16x16x32_bf16(av0, bc1, z, 0, 0, 0);
        f32x4 x11 = __builtin_amdgcn_mfma_f32_16x16x32_bf16(av1, bc1, z, 0, 0, 0);
        *(u16x4*)&qc[swz(lm, rb)]           = pack4(x00);
        *(u16x4*)&qc[swz(lm, 16 + rb)]      = pack4(x10);
        *(u16x4*)&qc[swz(16 + lm, rb)]      = pack4(x01);
        *(u16x4*)&qc[swz(16 + lm, 16 + rb)] = pack4(x11);
    }

    // ---- prefetch Wproj fragments + bias, then the cross-head barrier -----
    bf16x8 pw[2][4];
    float pb[2];
    #pragma unroll
    for (int t = 0; t < 2; ++t) {
        int col = w * 32 + t * 16 + lm;
        pb[t] = bproj[col];
        #pragma unroll
        for (int kk = 0; kk < 4; ++kk)
            pw[t][kk] = *(const bf16x8*)(wproj_b + col * CH + kk * 32 + ak);
    }
    __syncthreads();

    // ---- Phase 4: out = x_out @ Wproj^T + bproj ---------------------------
    {
        bf16x8 a2[2][4];
        #pragma unroll
        for (int kk = 0; kk < 4; ++kk) {
            a2[0][kk] = *(const bf16x8*)&Rq[kk * 1024 + swz(lm, ak)];
            a2[1][kk] = *(const bf16x8*)&Rq[kk * 1024 + swz(16 + lm, ak)];
        }
        float* ob = out + (size_t)b * BS * CH;
        #pragma unroll
        for (int t = 0; t < 2; ++t) {
            int col = w * 32 + t * 16 + lm;
            f32x4 acc0 = {pb[t], pb[t], pb[t], pb[t]};
            f32x4 acc1 = acc0;
            #pragma unroll
            for (int kk = 0; kk < 4; ++kk) {
                acc0 = __builtin_amdgcn_mfma_f32_16x16x32_bf16(a2[0][kk], pw[t][kk], acc0, 0, 0, 0);
                acc1 = __builtin_amdgcn_mfma_f32_16x16x32_bf16(a2[1][kk], pw[t][kk], acc1, 0, 0, 0);
            }
            #pragma unroll
            for (int j = 0; j < 4; ++j) {
                ob[(rb + j) * CH + col]      = acc0[j];
                ob[(16 + rb + j) * CH + col] = acc1[j];
            }
        }
    }
}

extern "C" void kernel_launch(void* const* d_in, const int* in_sizes, int n_in,
                              void* d_out, int out_size, void* d_ws, size_t ws_size,
                              hipStream_t stream) {
    const float* x          = (const float*)d_in[0];
    const float* edge_feats = (const float*)d_in[1];
    const float* Wqkv       = (const float*)d_in[2];
    const float* bqkv       = (const float*)d_in[3];
    const float* Wproj      = (const float*)d_in[4];
    const float* bproj      = (const float*)d_in[5];
    const float* Wgate      = (const float*)d_in[6];
    const float* bgate      = (const float*)d_in[7];
    const int*   attn_mask  = (const int*)d_in[8];
    float* out = (float*)d_out;
    short* wb  = (short*)d_ws;

    convert_weights<<<256, 256, 0, stream>>>(Wqkv, Wproj, wb);
    fused_block_attn<<<NBLK, 256, 0, stream>>>(
        x, edge_feats, bqkv, bproj, Wgate, bgate, attn_mask,
        wb, wb + 3 * CH * CH, out);
}